// Round 7
// baseline (1983.716 us; speedup 1.0000x reference)
//
#include <hip/hip_runtime.h>
#include <math.h>

// B=4096, L=64, H=64, V=21, NH=4, HD=16, FF=128, NL=2
constexpr int BATCH = 4096;

// ---------------- LDS regions (float indices), total 39,936 B
// A  [0,4352):    h row-major stride 68  /  gK row-major stride 68
// Bb [4352,8704): gQ row-major s68 / {QH,KH,VH 64x20} / F row-major s68 / hR s68
// M  [8704,9984): masks, scan state, LN partials
constexpr int A    = 0;
constexpr int Bb   = 4352;
constexpr int QH   = Bb;            // 64x20
constexpr int KH   = Bb + 1280;     // 64x20 (K, then O per head)
constexpr int VH   = Bb + 2560;     // 64x20
constexpr int MB   = 8704;
constexpr int M_MASK = MB + 0;
constexpr int M_DVAL = MB + 64;
constexpr int M_ISD  = MB + 128;
constexpr int M_SD   = MB + 192;    // final rw
constexpr int M_NBU  = MB + 256;    // pooled
constexpr int M_DG   = MB + 320;    // scalars
constexpr int M_DVEC = MB + 384;    // g diagonal
constexpr int M_S    = MB + 448;    // prefix sums
constexpr int M_PRU  = MB + 512;    // prior g[i,i+1]
constexpr int M_PRD  = MB + 576;    // prior g[i,i]
constexpr int M_SU   = MB + 640;    // s_up
constexpr int M_SDN  = MB + 704;    // s_dn
constexpr int PS     = MB + 768;    // 4x64 LN partial sums
constexpr int PSQ    = MB + 1024;   // 4x64 LN partial sumsq
constexpr int LDSN   = MB + 1280;   // 9984 floats = 39,936 B

// ---------------- output layout (floats) ----------------
constexpr int O_RES   = 0;
constexpr int O_REMB  = 4096;
constexpr int O_VALID = 266240;
constexpr int O_LEFT  = 270336;
constexpr int O_RIGHT = 274432;
constexpr int O_OPL   = 278528;
constexpr int O_RW    = 294912;

// LN of xr -> row-major stride-68 store at BASE. 2 barriers.
#define LN_ROW(GPTR, BPTR, BASE) do {                                     \
    float s_ = 0.f, q_ = 0.f;                                             \
    _Pragma("unroll") for (int j = 0; j < 16; ++j) {                      \
        s_ += xr[j]; q_ = fmaf(xr[j], xr[j], q_); }                       \
    lds[PS  + (wv << 6) + lane] = s_;                                     \
    lds[PSQ + (wv << 6) + lane] = q_;                                     \
    __syncthreads();                                                      \
    float fs_ = lds[PS + lane] + lds[PS + 64 + lane]                      \
              + lds[PS + 128 + lane] + lds[PS + 192 + lane];              \
    float fq_ = lds[PSQ + lane] + lds[PSQ + 64 + lane]                    \
              + lds[PSQ + 128 + lane] + lds[PSQ + 192 + lane];            \
    float mu_ = fs_ * 0.015625f;                                          \
    float inv_ = rsqrtf(fq_ * 0.015625f - mu_ * mu_ + 1e-6f);             \
    float hvv[16];                                                        \
    _Pragma("unroll") for (int j = 0; j < 16; ++j)                        \
        hvv[j] = (xr[j] - mu_) * inv_ * (GPTR)[c0 + j] + (BPTR)[c0 + j];  \
    _Pragma("unroll") for (int c4 = 0; c4 < 4; ++c4)                      \
        *reinterpret_cast<float4*>(&lds[(BASE) + lane * 68 + c0 + (c4 << 2)]) = \
            make_float4(hvv[(c4<<2)], hvv[(c4<<2)+1], hvv[(c4<<2)+2], hvv[(c4<<2)+3]); \
    __syncthreads();                                                      \
} while (0)

__global__ void __launch_bounds__(256, 2) fsa_kernel(
    const int* __restrict__ tok,
    const float* __restrict__ emb, const float* __restrict__ np_w, const float* __restrict__ np_b,
    const float* __restrict__ grp_wq, const float* __restrict__ grp_bq,
    const float* __restrict__ grp_wk, const float* __restrict__ grp_bk,
    const float* __restrict__ grp_ln_g, const float* __restrict__ grp_ln_b,
    const float* __restrict__ attn_w, const float* __restrict__ attn_b,
    const float* __restrict__ ln1_g, const float* __restrict__ ln1_b,
    const float* __restrict__ ln2_g, const float* __restrict__ ln2_b,
    const float* __restrict__ ffn_w1, const float* __restrict__ ffn_b1,
    const float* __restrict__ ffn_w2, const float* __restrict__ ffn_b2,
    const float* __restrict__ enc_g, const float* __restrict__ enc_b,
    const float* __restrict__ red_w, const float* __restrict__ red_b,
    const float* __restrict__ opc_w, const float* __restrict__ opc_b,
    const float* __restrict__ res_w, const float* __restrict__ res_b,
    float* __restrict__ out)
{
    __shared__ __align__(16) float lds[LDSN];
    const int b = blockIdx.x;
    const int tid = threadIdx.x;
    const int lane = tid & 63;
    const int wv = __builtin_amdgcn_readfirstlane(tid >> 6);
    const int c0 = wv << 4;
    const int wv4 = wv << 2;
    const int rl = tid >> 3;      // 0..31
    const int jg = tid & 7;       // score-col group: j = ju*8 + jg
    float xr[16];                 // x[lane][c0 .. c0+15] in registers

    // ================= embedding + positional encoding =================
    {
        int t = tok[(b << 6) + lane];
        float mk  = (t != 0) ? 1.f : 0.f;
        float isd = (t >= 4 && t <= 13) ? 1.f : 0.f;
        float dvv = ((float)t - 4.f) * isd;
        float iso = (t >= 14 && t <= 17) ? 1.f : 0.f;
        float opt = iso * ((float)t - 13.f);
        if (wv == 0) {
            lds[M_MASK + lane] = mk;  lds[M_DVAL + lane] = dvv; lds[M_ISD + lane] = isd;
            lds[M_PRU + lane] = 0.f;  lds[M_PRD + lane] = 0.f;
        }
        const float lg = -0.143911568f;   // -ln(10000)/64
        #pragma unroll
        for (int j = 0; j < 16; ++j) {
            int c = c0 + j;
            float freq = expf((float)(c & ~1) * lg);
            float ang = (float)lane * freq;
            float pe = (c & 1) ? cosf(ang) : sinf(ang);
            xr[j] = emb[t * 64 + c] * 8.f
                  + dvv * np_w[c] + isd * np_w[64 + c]
                  + opt * np_w[128 + c] + iso * np_w[192 + c]
                  + np_b[c] + pe;
        }
    }
    __syncthreads();
    // layer-invariant pairmask bits for this thread's jg slice
    int mbits = 0;
    #pragma unroll
    for (int ju = 0; ju < 8; ++ju)
        mbits |= (lds[M_MASK + ju * 8 + jg] > 0.f) ? (1 << ju) : 0;

    // ================= transformer layers =================
    for (int il = 0; il < 2; ++il) {
        const float* gwq = grp_wq + il * 4096; const float* gbq = grp_bq + (il << 6);
        const float* gwk = grp_wk + il * 4096; const float* gbk = grp_bk + (il << 6);
        const float* glg = grp_ln_g + (il << 6); const float* glb = grp_ln_b + (il << 6);
        const float* aw  = attn_w + il * 16384;  const float* ab  = attn_b + (il << 8);
        const float* l1g = ln1_g + (il << 6);    const float* l1b = ln1_b + (il << 6);
        const float* l2g = ln2_g + (il << 6);    const float* l2b = ln2_b + (il << 6);
        const float* fw1 = ffn_w1 + il * 8192;   const float* fb1 = ffn_b1 + (il << 7);
        const float* fw2 = ffn_w2 + il * 8192;   const float* fb2 = ffn_b2 + (il << 6);

        // ---- group (constituent) attention ----
        LN_ROW(glg, glb, A);
        {   // fused gQ/gK GEMM, b128 h reads
            float qa[16], ka[16];
            #pragma unroll
            for (int j = 0; j < 16; ++j) { qa[j] = gbq[c0 + j]; ka[j] = gbk[c0 + j]; }
            #pragma unroll
            for (int kb = 0; kb < 16; ++kb) {
                float4 hv = *reinterpret_cast<const float4*>(&lds[A + lane * 68 + (kb << 2)]);
                float ax[4] = {hv.x, hv.y, hv.z, hv.w};
                #pragma unroll
                for (int e = 0; e < 4; ++e) {
                    int kk = (kb << 2) + e;
                    const float* wq = gwq + kk * 64 + c0;
                    const float* wk = gwk + kk * 64 + c0;
                    #pragma unroll
                    for (int j = 0; j < 16; ++j) {
                        qa[j] = fmaf(ax[e], wq[j], qa[j]);
                        ka[j] = fmaf(ax[e], wk[j], ka[j]);
                    }
                }
            }
            #pragma unroll
            for (int c4 = 0; c4 < 4; ++c4)
                *reinterpret_cast<float4*>(&lds[Bb + lane * 68 + c0 + (c4 << 2)]) =
                    make_float4(qa[(c4<<2)], qa[(c4<<2)+1], qa[(c4<<2)+2], qa[(c4<<2)+3]);
            __syncthreads();          // h reads done; gQ visible
            #pragma unroll
            for (int c4 = 0; c4 < 4; ++c4)
                *reinterpret_cast<float4*>(&lds[A + lane * 68 + c0 + (c4 << 2)]) =
                    make_float4(ka[(c4<<2)], ka[(c4<<2)+1], ka[(c4<<2)+2], ka[(c4<<2)+3]);
            __syncthreads();
        }

        if (tid < 126) {              // s[i,i+1] and s[i+1,i], b128 row dots
            int i = tid >> 1, w = tid & 1;
            int ra = w ? i + 1 : i, rb = w ? i : i + 1;
            float s = 0.f;
            #pragma unroll
            for (int c4 = 0; c4 < 16; ++c4) {
                float4 qv = *reinterpret_cast<const float4*>(&lds[Bb + ra * 68 + (c4 << 2)]);
                float4 kv = *reinterpret_cast<const float4*>(&lds[A  + rb * 68 + (c4 << 2)]);
                s = fmaf(qv.x, kv.x, s); s = fmaf(qv.y, kv.y, s);
                s = fmaf(qv.z, kv.z, s); s = fmaf(qv.w, kv.w, s);
            }
            lds[(w ? M_SDN : M_SU) + i] = s * 0.125f;   // / sqrt(H)
        }
        __syncthreads();

        if (wv == 0) {   // merged: masked softmax + symmetrize + prior + shfl scan
            const int i = lane;
            float mi  = lds[M_MASK + i];
            float mup = (i < 63) ? lds[M_MASK + i + 1] : 0.f;
            float mdn = (i > 0)  ? lds[M_MASK + i - 1] : 0.f;
            float eu = (mi > 0.f && mup > 0.f) ? lds[M_SU + i] : -1e9f;
            float ed = (i > 0 && mi > 0.f && mdn > 0.f) ? lds[M_SDN + i - 1] : -1e9f;
            float m = fmaxf(eu, ed);
            float nu, nd, ng;
            if (m <= -1e9f) { nu = 0.015625f; nd = 0.015625f; ng = 0.015625f; }
            else {
                float zu = __expf(eu - m), zd = __expf(ed - m);
                float iz = 1.f / (zu + zd);
                nu = zu * iz; nd = zd * iz; ng = 0.f;
            }
            float nd1 = __shfl_down(nd, 1);       // nb_dn of row i+1
            float pd = lds[M_PRD + i];
            float dsym = sqrtf(ng * ng + 1e-9f);
            float d2 = pd + (1.f - pd) * dsym;
            lds[M_DVEC + i] = d2; lds[M_PRD + i] = d2;
            float la = 0.f;
            if (i < 63) {
                float pu = lds[M_PRU + i];
                float as_ = sqrtf(nu * nd1 + 1e-9f);
                float a2 = pu + (1.f - pu) * as_;
                la = logf(a2 + 1e-9f);
                lds[M_PRU + i] = __expf(la) + 1e-9f;   // next-layer prior
            }
            float x = __shfl_up(la, 1);
            if (i == 0) x = 0.f;
            #pragma unroll
            for (int off = 1; off < 64; off <<= 1) {
                float t2 = __shfl_up(x, off);
                if (i >= off) x += t2;
            }
            lds[M_S + i] = x;                     // S[i] = sum_{k<i} la[k]
        }
        __syncthreads();

        // ---- multi-head attention, weighted by g (heads outer) ----
        LN_ROW(l1g, l1b, A);
        // hoist head-invariant g weights into registers (16 exp/layer)
        float g0[8], g1[8];
        {
            float Sr0 = lds[M_S + rl], Sr1 = lds[M_S + rl + 32];
            float dv0 = lds[M_DVEC + rl], dv1 = lds[M_DVEC + rl + 32];
            #pragma unroll
            for (int ju = 0; ju < 8; ++ju) {
                int jj = ju * 8 + jg;
                float Sj = lds[M_S + jj];
                g0[ju] = (jj == rl)      ? dv0 : (__expf((jj > rl)      ? (Sj - Sr0) : (Sr0 - Sj)) + 1e-9f);
                g1[ju] = (jj == rl + 32) ? dv1 : (__expf((jj > rl + 32) ? (Sj - Sr1) : (Sr1 - Sj)) + 1e-9f);
            }
        }
        for (int hh = 0; hh < 4; ++hh) {
            const int hb = hh << 4;
            // per-head QKV GEMM, b128 h reads
            float q4[4], k4[4], v4[4];
            #pragma unroll
            for (int j = 0; j < 4; ++j) {
                q4[j] = ab[hb + wv4 + j];
                k4[j] = ab[64 + hb + wv4 + j];
                v4[j] = ab[128 + hb + wv4 + j];
            }
            #pragma unroll
            for (int kb = 0; kb < 16; ++kb) {
                float4 hv = *reinterpret_cast<const float4*>(&lds[A + lane * 68 + (kb << 2)]);
                float ax[4] = {hv.x, hv.y, hv.z, hv.w};
                #pragma unroll
                for (int e = 0; e < 4; ++e) {
                    int kk = (kb << 2) + e;
                    const float* wq  = aw + kk * 64 + hb + wv4;
                    const float* wk  = aw + 4096 + kk * 64 + hb + wv4;
                    const float* wvp = aw + 8192 + kk * 64 + hb + wv4;
                    #pragma unroll
                    for (int j = 0; j < 4; ++j) {
                        q4[j] = fmaf(ax[e], wq[j], q4[j]);
                        k4[j] = fmaf(ax[e], wk[j], k4[j]);
                        v4[j] = fmaf(ax[e], wvp[j], v4[j]);
                    }
                }
            }
            if (hh) __syncthreads();  // prev head's QH/KH(O)/VH reads done
            *reinterpret_cast<float4*>(&lds[QH + lane * 20 + wv4]) = make_float4(q4[0], q4[1], q4[2], q4[3]);
            *reinterpret_cast<float4*>(&lds[KH + lane * 20 + wv4]) = make_float4(k4[0], k4[1], k4[2], k4[3]);
            *reinterpret_cast<float4*>(&lds[VH + lane * 20 + wv4]) = make_float4(v4[0], v4[1], v4[2], v4[3]);
            __syncthreads();

            // q rows rl and rl+32
            float q0[16], q1[16];
            #pragma unroll
            for (int c4 = 0; c4 < 4; ++c4) {
                float4 a0 = *reinterpret_cast<const float4*>(&lds[QH + rl * 20 + (c4 << 2)]);
                float4 a1 = *reinterpret_cast<const float4*>(&lds[QH + (rl + 32) * 20 + (c4 << 2)]);
                q0[(c4<<2)+0] = a0.x; q0[(c4<<2)+1] = a0.y; q0[(c4<<2)+2] = a0.z; q0[(c4<<2)+3] = a0.w;
                q1[(c4<<2)+0] = a1.x; q1[(c4<<2)+1] = a1.y; q1[(c4<<2)+2] = a1.z; q1[(c4<<2)+3] = a1.w;
            }
            float sc0[8], sc1[8];
            #pragma unroll
            for (int ju = 0; ju < 8; ++ju) {
                float s0 = 0.f, s1 = 0.f;
                #pragma unroll
                for (int c4 = 0; c4 < 4; ++c4) {
                    const float4 kv = *reinterpret_cast<const float4*>(
                        &lds[KH + (ju * 8 + jg) * 20 + (c4 << 2)]);
                    s0 = fmaf(q0[(c4<<2)+0], kv.x, s0); s0 = fmaf(q0[(c4<<2)+1], kv.y, s0);
                    s0 = fmaf(q0[(c4<<2)+2], kv.z, s0); s0 = fmaf(q0[(c4<<2)+3], kv.w, s0);
                    s1 = fmaf(q1[(c4<<2)+0], kv.x, s1); s1 = fmaf(q1[(c4<<2)+1], kv.y, s1);
                    s1 = fmaf(q1[(c4<<2)+2], kv.z, s1); s1 = fmaf(q1[(c4<<2)+3], kv.w, s1);
                }
                sc0[ju] = s0; sc1[ju] = s1;
            }
            float m0 = -1e9f, m1 = -1e9f;
            #pragma unroll
            for (int ju = 0; ju < 8; ++ju) {
                bool mk = (mbits >> ju) & 1;
                sc0[ju] = mk ? sc0[ju] * 0.25f : -1e9f;
                sc1[ju] = mk ? sc1[ju] * 0.25f : -1e9f;
                m0 = fmaxf(m0, sc0[ju]); m1 = fmaxf(m1, sc1[ju]);
            }
            m0 = fmaxf(m0, __shfl_xor(m0, 1)); m0 = fmaxf(m0, __shfl_xor(m0, 2)); m0 = fmaxf(m0, __shfl_xor(m0, 4));
            m1 = fmaxf(m1, __shfl_xor(m1, 1)); m1 = fmaxf(m1, __shfl_xor(m1, 2)); m1 = fmaxf(m1, __shfl_xor(m1, 4));
            float z0 = 0.f, z1 = 0.f;
            float p0[8], p1[8];
            #pragma unroll
            for (int ju = 0; ju < 8; ++ju) {
                p0[ju] = __expf(sc0[ju] - m0); z0 += p0[ju];
                p1[ju] = __expf(sc1[ju] - m1); z1 += p1[ju];
            }
            z0 += __shfl_xor(z0, 1); z0 += __shfl_xor(z0, 2); z0 += __shfl_xor(z0, 4);
            z1 += __shfl_xor(z1, 1); z1 += __shfl_xor(z1, 2); z1 += __shfl_xor(z1, 4);
            float iz0 = 1.f / z0, iz1 = 1.f / z1;
            #pragma unroll
            for (int ju = 0; ju < 8; ++ju) {
                p0[ju] = p0[ju] * iz0 * g0[ju];
                p1[ju] = p1[ju] * iz1 * g1[ju];
            }
            float po0[16], po1[16];
            #pragma unroll
            for (int c = 0; c < 16; ++c) { po0[c] = 0.f; po1[c] = 0.f; }
            #pragma unroll
            for (int ju = 0; ju < 8; ++ju) {
                #pragma unroll
                for (int c4 = 0; c4 < 4; ++c4) {
                    const float4 v = *reinterpret_cast<const float4*>(
                        &lds[VH + (ju * 8 + jg) * 20 + (c4 << 2)]);
                    po0[(c4<<2)+0] = fmaf(p0[ju], v.x, po0[(c4<<2)+0]);
                    po0[(c4<<2)+1] = fmaf(p0[ju], v.y, po0[(c4<<2)+1]);
                    po0[(c4<<2)+2] = fmaf(p0[ju], v.z, po0[(c4<<2)+2]);
                    po0[(c4<<2)+3] = fmaf(p0[ju], v.w, po0[(c4<<2)+3]);
                    po1[(c4<<2)+0] = fmaf(p1[ju], v.x, po1[(c4<<2)+0]);
                    po1[(c4<<2)+1] = fmaf(p1[ju], v.y, po1[(c4<<2)+1]);
                    po1[(c4<<2)+2] = fmaf(p1[ju], v.z, po1[(c4<<2)+2]);
                    po1[(c4<<2)+3] = fmaf(p1[ju], v.w, po1[(c4<<2)+3]);
                }
            }
            #pragma unroll
            for (int c = 0; c < 16; ++c) {
                po0[c] += __shfl_xor(po0[c], 1); po0[c] += __shfl_xor(po0[c], 2); po0[c] += __shfl_xor(po0[c], 4);
                po1[c] += __shfl_xor(po1[c], 1); po1[c] += __shfl_xor(po1[c], 2); po1[c] += __shfl_xor(po1[c], 4);
            }
            __syncthreads();          // all KH (score) reads done
            if (jg == 0) {            // O_h overwrites KH (K dead)
                #pragma unroll
                for (int c4 = 0; c4 < 4; ++c4) {
                    *reinterpret_cast<float4*>(&lds[KH + rl * 20 + (c4 << 2)]) =
                        make_float4(po0[(c4<<2)], po0[(c4<<2)+1], po0[(c4<<2)+2], po0[(c4<<2)+3]);
                    *reinterpret_cast<float4*>(&lds[KH + (rl + 32) * 20 + (c4 << 2)]) =
                        make_float4(po1[(c4<<2)], po1[(c4<<2)+1], po1[(c4<<2)+2], po1[(c4<<2)+3]);
                }
            }
            __syncthreads();
            // O-proj slice: xr += O_h @ Wo[hb:hb+16, :]
            {
                const float* Wo = aw + 12288; const float* bo = ab + 192;
                float oh[16];
                #pragma unroll
                for (int c4 = 0; c4 < 4; ++c4) {
                    float4 o4 = *reinterpret_cast<const float4*>(&lds[KH + lane * 20 + (c4 << 2)]);
                    oh[(c4<<2)+0] = o4.x; oh[(c4<<2)+1] = o4.y; oh[(c4<<2)+2] = o4.z; oh[(c4<<2)+3] = o4.w;
                }
                float acc[16];
                #pragma unroll
                for (int j = 0; j < 16; ++j) acc[j] = (hh == 0) ? bo[c0 + j] : 0.f;
                #pragma unroll
                for (int d = 0; d < 16; ++d) {
                    const float* wr = Wo + (hb + d) * 64 + c0;
                    #pragma unroll
                    for (int j = 0; j < 16; ++j) acc[j] = fmaf(oh[d], wr[j], acc[j]);
                }
                #pragma unroll
                for (int j = 0; j < 16; ++j) xr[j] += acc[j];
            }
        }

        // ---- FFN (two 64-col halves of F share one buffer, row-major s68) ----
        LN_ROW(l2g, l2b, A);
        #pragma unroll
        for (int half = 0; half < 2; ++half) {
            const int co = half << 6;
            {   // F-half = relu(h @ W1[:, co+c0 ...])
                float fa[16];
                #pragma unroll
                for (int j = 0; j < 16; ++j) fa[j] = fb1[co + c0 + j];
                #pragma unroll
                for (int kb = 0; kb < 16; ++kb) {
                    float4 hv = *reinterpret_cast<const float4*>(&lds[A + lane * 68 + (kb << 2)]);
                    float ax[4] = {hv.x, hv.y, hv.z, hv.w};
                    #pragma unroll
                    for (int e = 0; e < 4; ++e) {
                        int kk = (kb << 2) + e;
                        const float* wr = fw1 + kk * 128 + co + c0;
                        #pragma unroll
                        for (int j = 0; j < 16; ++j) fa[j] = fmaf(ax[e], wr[j], fa[j]);
                    }
                }
                #pragma unroll
                for (int c4 = 0; c4 < 4; ++c4)
                    *reinterpret_cast<float4*>(&lds[Bb + lane * 68 + c0 + (c4 << 2)]) =
                        make_float4(fmaxf(fa[(c4<<2)], 0.f), fmaxf(fa[(c4<<2)+1], 0.f),
                                    fmaxf(fa[(c4<<2)+2], 0.f), fmaxf(fa[(c4<<2)+3], 0.f));
            }
            __syncthreads();
            {   // xr += F-half @ W2[co:co+64]
                float acc[16];
                #pragma unroll
                for (int j = 0; j < 16; ++j) acc[j] = (half == 0) ? fb2[c0 + j] : 0.f;
                #pragma unroll
                for (int kb = 0; kb < 16; ++kb) {
                    float4 fv = *reinterpret_cast<const float4*>(&lds[Bb + lane * 68 + (kb << 2)]);
                    float ax[4] = {fv.x, fv.y, fv.z, fv.w};
                    #pragma unroll
                    for (int e = 0; e < 4; ++e) {
                        int kk = (kb << 2) + e;
                        const float* wr = fw2 + (co + kk) * 64 + c0;
                        #pragma unroll
                        for (int j = 0; j < 16; ++j) acc[j] = fmaf(ax[e], wr[j], acc[j]);
                    }
                }
                #pragma unroll
                for (int j = 0; j < 16; ++j) xr[j] += acc[j];
            }
            __syncthreads();
        }
    }

    // ================= reduction / calculator head =================
    LN_ROW(enc_g, enc_b, Bb);   // final h row-major stride 68
    if (tid < 64) {       // scores = h @ red_w + red_b + (1-mask)*-1e9
        float s = 0.f;
        #pragma unroll
        for (int c4 = 0; c4 < 16; ++c4) {
            float4 hv = *reinterpret_cast<const float4*>(&lds[Bb + tid * 68 + (c4 << 2)]);
            float4 rv = *reinterpret_cast<const float4*>(&red_w[c4 << 2]);
            s = fmaf(hv.x, rv.x, s); s = fmaf(hv.y, rv.y, s);
            s = fmaf(hv.z, rv.z, s); s = fmaf(hv.w, rv.w, s);
        }
        s += red_b[0];
        s += (1.f - lds[M_MASK + tid]) * -1e9f;
        lds[M_SU + tid] = s;
    }
    __syncthreads();

    if (wv == 0) {        // softmax, scans, digit assembly (wave 0)
        float s = lds[M_SU + lane];
        float m = s;
        #pragma unroll
        for (int off = 1; off < 64; off <<= 1) m = fmaxf(m, __shfl_xor(m, off));
        float ee = expf(s - m);
        float z = ee;
        #pragma unroll
        for (int off = 1; off < 64; off <<= 1) z += __shfl_xor(z, off);
        float rw = ee / z;
        lds[M_SD + lane] = rw;
        float cum = rw;
        #pragma unroll
        for (int off = 1; off < 64; off <<= 1) { float t2 = __shfl_up(cum, off); if (lane >= off) cum += t2; }
        float isd = lds[M_ISD + lane], dvv = lds[M_DVAL + lane];
        float lm = (1.f - cum) * isd;
        float rm = (cum - rw) * isd;
        float cl = lm;
        #pragma unroll
        for (int off = 1; off < 64; off <<= 1) { float t2 = __shfl_up(cl, off); if (lane >= off) cl += t2; }
        float totl = __shfl(cl, 63);
        float wL = powf(10.f, (totl - cl) * lm) * lm;
        float lv = dvv * wL;
        #pragma unroll
        for (int off = 1; off < 64; off <<= 1) lv += __shfl_xor(lv, off);
        float cr = rm;
        #pragma unroll
        for (int off = 1; off < 64; off <<= 1) { float t2 = __shfl_up(cr, off); if (lane >= off) cr += t2; }
        float totr = __shfl(cr, 63);
        float wR = powf(10.f, (totr - cr) * rm) * rm;
        float rv = dvv * wR;
        #pragma unroll
        for (int off = 1; off < 64; off <<= 1) rv += __shfl_xor(rv, off);
        if (lane == 0) { lds[M_DG + 2] = lv; lds[M_DG + 3] = rv; }
    }
    __syncthreads();

    if (tid < 64) {       // pooled[c] = sum_r h[r][c] * rw[r]
        float p = 0.f;
        #pragma unroll 8
        for (int r2 = 0; r2 < 64; ++r2)
            p = fmaf(lds[Bb + r2 * 68 + tid], lds[M_SD + r2], p);
        lds[M_NBU + tid] = p;
    }
    __syncthreads();
    if (tid < 4) {        // op logits
        float s = opc_b[tid];
        for (int c2 = 0; c2 < 64; ++c2) s = fmaf(lds[M_NBU + c2], opc_w[(c2 << 2) + tid], s);
        lds[M_DG + 4 + tid] = s;
    }
    __syncthreads();
    if (tid == 0) {       // hard argmax op select + fixed ops
        float l = lds[M_DG + 2], r = lds[M_DG + 3];
        float o0 = lds[M_DG + 4], o1 = lds[M_DG + 5], o2 = lds[M_DG + 6], o3 = lds[M_DG + 7];
        int op = 0; float bm = o0;
        if (o1 > bm) { bm = o1; op = 1; }
        if (o2 > bm) { bm = o2; op = 2; }
        if (o3 > bm) { bm = o3; op = 3; }
        float res, vl = 1.f;
        if (op == 0)      res = l + r;
        else if (op == 1) res = l - r;
        else if (op == 2) res = l * r;
        else { bool bad = fabsf(r) < 1e-6f; res = bad ? 0.f : (l / r); vl = bad ? 0.f : 1.f; }
        float rc = (res > 0.f) ? log1pf(res) : ((res < 0.f) ? -log1pf(-res) : 0.f);
        lds[M_DG + 0] = rc; lds[M_DG + 1] = vl;
        out[O_RES + b]   = res;
        out[O_VALID + b] = vl;
        out[O_LEFT + b]  = l;
        out[O_RIGHT + b] = r;
    }
    __syncthreads();
    if (tid < 64) {
        float rc = lds[M_DG + 0], vl = lds[M_DG + 1];
        out[O_REMB + (b << 6) + tid] = rc * res_w[tid] + vl * res_w[64 + tid] + res_b[tid];
        out[O_RW + (b << 6) + tid] = lds[M_SD + tid];
    }
    if (tid >= 64 && tid < 68) {
        int o = tid - 64;
        out[O_OPL + (b << 2) + o] = lds[M_DG + 4 + o];
    }
}

extern "C" void kernel_launch(void* const* d_in, const int* in_sizes, int n_in,
                              void* d_out, int out_size, void* d_ws, size_t ws_size,
                              hipStream_t stream)
{
    fsa_kernel<<<dim3(BATCH), dim3(256), 0, stream>>>(
        (const int*)d_in[0],
        (const float*)d_in[1],  (const float*)d_in[2],  (const float*)d_in[3],
        (const float*)d_in[4],  (const float*)d_in[5],  (const float*)d_in[6],  (const float*)d_in[7],
        (const float*)d_in[8],  (const float*)d_in[9],  (const float*)d_in[10], (const float*)d_in[11],
        (const float*)d_in[12], (const float*)d_in[13], (const float*)d_in[14], (const float*)d_in[15],
        (const float*)d_in[16], (const float*)d_in[17], (const float*)d_in[18], (const float*)d_in[19],
        (const float*)d_in[20], (const float*)d_in[21], (const float*)d_in[22], (const float*)d_in[23],
        (const float*)d_in[24], (const float*)d_in[25], (const float*)d_in[26], (const float*)d_in[27],
        (float*)d_out);
}

// Round 8
// 1430.124 us; speedup vs baseline: 1.3871x; 1.3871x over previous
//
#include <hip/hip_runtime.h>
#include <math.h>

// B=4096, L=64, H=64, V=21, NH=4, HD=16, FF=128, NL=2
constexpr int BATCH = 4096;

// ---------------- LDS regions (float indices), total 39,936 B -> 4 blocks/CU
// A  [0,4352):    hT [c][r] stride 64  /  gK^T stride 64
// Bb [4352,8704): gQ^T stride 64 / {QH,KH,VH 64x20} / F^T stride 64 / hR stride 65
// M  [8704,9984): masks, scan state, LN partials
constexpr int A    = 0;
constexpr int Bb   = 4352;
constexpr int QH   = Bb;            // 64x20
constexpr int KH   = Bb + 1280;     // 64x20
constexpr int VH   = Bb + 2560;     // 64x20
constexpr int MB   = 8704;
constexpr int M_MASK = MB + 0;
constexpr int M_DVAL = MB + 64;
constexpr int M_ISD  = MB + 128;
constexpr int M_SD   = MB + 192;    // final rw
constexpr int M_NBU  = MB + 256;    // pooled
constexpr int M_DG   = MB + 320;    // scalars
constexpr int M_DVEC = MB + 384;    // g diagonal
constexpr int M_S    = MB + 448;    // prefix sums
constexpr int M_PRU  = MB + 512;    // prior g[i,i+1]
constexpr int M_PRD  = MB + 576;    // prior g[i,i]
constexpr int M_SU   = MB + 640;    // s_up
constexpr int M_SDN  = MB + 704;    // s_dn
constexpr int PS     = MB + 768;    // 4x64 LN partial sums
constexpr int PSQ    = MB + 1024;   // 4x64 LN partial sumsq
constexpr int LDSN   = MB + 1280;   // 9984 floats = 39,936 B

// ---------------- output layout (floats) ----------------
constexpr int O_RES   = 0;
constexpr int O_REMB  = 4096;
constexpr int O_VALID = 266240;
constexpr int O_LEFT  = 270336;
constexpr int O_RIGHT = 274432;
constexpr int O_OPL   = 278528;
constexpr int O_RW    = 294912;

// LN of xr; stats via 4-wave LDS partial reduce; then STORE per column.
#define LN_STORE(GPTR, BPTR, STORE) do {                                  \
    float s_ = 0.f, q_ = 0.f;                                             \
    _Pragma("unroll") for (int j = 0; j < 16; ++j) {                      \
        s_ += xr[j]; q_ = fmaf(xr[j], xr[j], q_); }                       \
    lds[PS  + (wv << 6) + lane] = s_;                                     \
    lds[PSQ + (wv << 6) + lane] = q_;                                     \
    __syncthreads();                                                      \
    float fs_ = lds[PS + lane] + lds[PS + 64 + lane]                      \
              + lds[PS + 128 + lane] + lds[PS + 192 + lane];              \
    float fq_ = lds[PSQ + lane] + lds[PSQ + 64 + lane]                    \
              + lds[PSQ + 128 + lane] + lds[PSQ + 192 + lane];            \
    float mu_ = fs_ * 0.015625f;                                          \
    float inv_ = rsqrtf(fq_ * 0.015625f - mu_ * mu_ + 1e-6f);             \
    _Pragma("unroll") for (int j = 0; j < 16; ++j) {                      \
        int c_ = c0 + j;                                                  \
        float hv_ = (xr[j] - mu_) * inv_ * (GPTR)[c_] + (BPTR)[c_];       \
        STORE;                                                            \
    }                                                                     \
    __syncthreads();                                                      \
} while (0)

__global__ void __launch_bounds__(256, 2) fsa_kernel(
    const int* __restrict__ tok,
    const float* __restrict__ emb, const float* __restrict__ np_w, const float* __restrict__ np_b,
    const float* __restrict__ grp_wq, const float* __restrict__ grp_bq,
    const float* __restrict__ grp_wk, const float* __restrict__ grp_bk,
    const float* __restrict__ grp_ln_g, const float* __restrict__ grp_ln_b,
    const float* __restrict__ attn_w, const float* __restrict__ attn_b,
    const float* __restrict__ ln1_g, const float* __restrict__ ln1_b,
    const float* __restrict__ ln2_g, const float* __restrict__ ln2_b,
    const float* __restrict__ ffn_w1, const float* __restrict__ ffn_b1,
    const float* __restrict__ ffn_w2, const float* __restrict__ ffn_b2,
    const float* __restrict__ enc_g, const float* __restrict__ enc_b,
    const float* __restrict__ red_w, const float* __restrict__ red_b,
    const float* __restrict__ opc_w, const float* __restrict__ opc_b,
    const float* __restrict__ res_w, const float* __restrict__ res_b,
    float* __restrict__ out)
{
    __shared__ __align__(16) float lds[LDSN];
    const int b = blockIdx.x;
    const int tid = threadIdx.x;
    const int lane = tid & 63;
    const int wv = __builtin_amdgcn_readfirstlane(tid >> 6);
    const int c0 = wv << 4;
    const int wv4 = wv << 2;
    const int rl = tid >> 3;      // 0..31
    const int jg = tid & 7;       // score-col group: j = ju*8 + jg
    float xr[16];                 // x[lane][c0 .. c0+15] in registers

    // ================= embedding + positional encoding =================
    {
        int t = tok[(b << 6) + lane];
        float mk  = (t != 0) ? 1.f : 0.f;
        float isd = (t >= 4 && t <= 13) ? 1.f : 0.f;
        float dvv = ((float)t - 4.f) * isd;
        float iso = (t >= 14 && t <= 17) ? 1.f : 0.f;
        float opt = iso * ((float)t - 13.f);
        if (wv == 0) {
            lds[M_MASK + lane] = mk;  lds[M_DVAL + lane] = dvv; lds[M_ISD + lane] = isd;
            lds[M_PRU + lane] = 0.f;  lds[M_PRD + lane] = 0.f;
        }
        const float lg = -0.143911568f;   // -ln(10000)/64
        #pragma unroll
        for (int j = 0; j < 16; ++j) {
            int c = c0 + j;
            float freq = expf((float)(c & ~1) * lg);
            float ang = (float)lane * freq;
            float pe = (c & 1) ? cosf(ang) : sinf(ang);
            xr[j] = emb[t * 64 + c] * 8.f
                  + dvv * np_w[c] + isd * np_w[64 + c]
                  + opt * np_w[128 + c] + iso * np_w[192 + c]
                  + np_b[c] + pe;
        }
    }
    __syncthreads();
    // layer-invariant pairmask bits for this thread's jg slice
    int mbits = 0;
    #pragma unroll
    for (int ju = 0; ju < 8; ++ju)
        mbits |= (lds[M_MASK + ju * 8 + jg] > 0.f) ? (1 << ju) : 0;

    // ================= transformer layers =================
    for (int il = 0; il < 2; ++il) {
        const float* gwq = grp_wq + il * 4096; const float* gbq = grp_bq + (il << 6);
        const float* gwk = grp_wk + il * 4096; const float* gbk = grp_bk + (il << 6);
        const float* glg = grp_ln_g + (il << 6); const float* glb = grp_ln_b + (il << 6);
        const float* aw  = attn_w + il * 16384;  const float* ab  = attn_b + (il << 8);
        const float* l1g = ln1_g + (il << 6);    const float* l1b = ln1_b + (il << 6);
        const float* l2g = ln2_g + (il << 6);    const float* l2b = ln2_b + (il << 6);
        const float* fw1 = ffn_w1 + il * 8192;   const float* fb1 = ffn_b1 + (il << 7);
        const float* fw2 = ffn_w2 + il * 8192;   const float* fb2 = ffn_b2 + (il << 6);

        // ---- group (constituent) attention ----
        LN_STORE(glg, glb, lds[A + c_ * 64 + lane] = hv_);
        {   // fused gQ/gK GEMM streaming hT
            float qa[16], ka[16];
            #pragma unroll
            for (int j = 0; j < 16; ++j) { qa[j] = gbq[c0 + j]; ka[j] = gbk[c0 + j]; }
            #pragma unroll 8
            for (int kk = 0; kk < 64; ++kk) {
                float a = lds[A + kk * 64 + lane];
                const float* wq = gwq + kk * 64 + c0;
                const float* wk = gwk + kk * 64 + c0;
                #pragma unroll
                for (int j = 0; j < 16; ++j) {
                    qa[j] = fmaf(a, wq[j], qa[j]);
                    ka[j] = fmaf(a, wk[j], ka[j]);
                }
            }
            #pragma unroll
            for (int j = 0; j < 16; ++j) lds[Bb + (c0 + j) * 64 + lane] = qa[j]; // gQ^T
            __syncthreads();          // hT reads done; gQ^T visible
            #pragma unroll
            for (int j = 0; j < 16; ++j) lds[A + (c0 + j) * 64 + lane] = ka[j];  // gK^T
            __syncthreads();
        }

        if (tid < 126) {              // s[i,i+1] and s[i+1,i]
            int i = tid >> 1, w = tid & 1;
            int ra = w ? i + 1 : i, rb = w ? i : i + 1;
            float s = 0.f;
            #pragma unroll 8
            for (int c2 = 0; c2 < 64; ++c2)
                s = fmaf(lds[Bb + c2 * 64 + ra], lds[A + c2 * 64 + rb], s);
            lds[(w ? M_SDN : M_SU) + i] = s * 0.125f;   // / sqrt(H)
        }
        __syncthreads();

        if (wv == 0) {   // merged: masked softmax + symmetrize + prior + shfl scan
            const int i = lane;
            float mi  = lds[M_MASK + i];
            float mup = (i < 63) ? lds[M_MASK + i + 1] : 0.f;
            float mdn = (i > 0)  ? lds[M_MASK + i - 1] : 0.f;
            float eu = (mi > 0.f && mup > 0.f) ? lds[M_SU + i] : -1e9f;
            float ed = (i > 0 && mi > 0.f && mdn > 0.f) ? lds[M_SDN + i - 1] : -1e9f;
            float m = fmaxf(eu, ed);
            float nu, nd, ng;
            if (m <= -1e9f) { nu = 0.015625f; nd = 0.015625f; ng = 0.015625f; }
            else {
                float zu = __expf(eu - m), zd = __expf(ed - m);
                float iz = 1.f / (zu + zd);
                nu = zu * iz; nd = zd * iz; ng = 0.f;
            }
            float nd1 = __shfl_down(nd, 1);       // nb_dn of row i+1
            float pd = lds[M_PRD + i];
            float dsym = sqrtf(ng * ng + 1e-9f);
            float d2 = pd + (1.f - pd) * dsym;
            lds[M_DVEC + i] = d2; lds[M_PRD + i] = d2;
            float la = 0.f;
            if (i < 63) {
                float pu = lds[M_PRU + i];
                float as_ = sqrtf(nu * nd1 + 1e-9f);
                float a2 = pu + (1.f - pu) * as_;
                la = logf(a2 + 1e-9f);
                lds[M_PRU + i] = __expf(la) + 1e-9f;   // next-layer prior
            }
            float x = __shfl_up(la, 1);
            if (i == 0) x = 0.f;
            #pragma unroll
            for (int off = 1; off < 64; off <<= 1) {
                float t2 = __shfl_up(x, off);
                if (i >= off) x += t2;
            }
            lds[M_S + i] = x;                     // S[i] = sum_{k<i} la[k]
        }
        __syncthreads();

        // ---- multi-head attention, weighted by g (heads outer) ----
        LN_STORE(l1g, l1b, lds[A + c_ * 64 + lane] = hv_);
        // hoist head-invariant g weights into registers (16 exp per thread, once)
        float g0[8], g1[8];
        {
            float Sr0 = lds[M_S + rl], Sr1 = lds[M_S + rl + 32];
            float dv0 = lds[M_DVEC + rl], dv1 = lds[M_DVEC + rl + 32];
            #pragma unroll
            for (int ju = 0; ju < 8; ++ju) {
                int jj = ju * 8 + jg;
                float Sj = lds[M_S + jj];
                g0[ju] = (jj == rl)      ? dv0 : (__expf((jj > rl)      ? (Sj - Sr0) : (Sr0 - Sj)) + 1e-9f);
                g1[ju] = (jj == rl + 32) ? dv1 : (__expf((jj > rl + 32) ? (Sj - Sr1) : (Sr1 - Sj)) + 1e-9f);
            }
        }
        for (int hh = 0; hh < 4; ++hh) {
            const int hb = hh << 4;
            // per-head QKV GEMM: this thread owns 4 cols of each
            float q4[4], k4[4], v4[4];
            #pragma unroll
            for (int j = 0; j < 4; ++j) {
                q4[j] = ab[hb + wv4 + j];
                k4[j] = ab[64 + hb + wv4 + j];
                v4[j] = ab[128 + hb + wv4 + j];
            }
            #pragma unroll 8
            for (int kk = 0; kk < 64; ++kk) {
                float a = lds[A + kk * 64 + lane];
                const float* wq  = aw + kk * 64 + hb + wv4;
                const float* wk  = aw + 4096 + kk * 64 + hb + wv4;
                const float* wvp = aw + 8192 + kk * 64 + hb + wv4;
                #pragma unroll
                for (int j = 0; j < 4; ++j) {
                    q4[j] = fmaf(a, wq[j], q4[j]);
                    k4[j] = fmaf(a, wk[j], k4[j]);
                    v4[j] = fmaf(a, wvp[j], v4[j]);
                }
            }
            __syncthreads();          // prev head's QH/KH/VH reads done
            *reinterpret_cast<float4*>(&lds[QH + lane * 20 + wv4]) = make_float4(q4[0], q4[1], q4[2], q4[3]);
            *reinterpret_cast<float4*>(&lds[KH + lane * 20 + wv4]) = make_float4(k4[0], k4[1], k4[2], k4[3]);
            *reinterpret_cast<float4*>(&lds[VH + lane * 20 + wv4]) = make_float4(v4[0], v4[1], v4[2], v4[3]);
            __syncthreads();

            // q rows rl and rl+32 (8-lane broadcast, conflict-free)
            float q0[16], q1[16];
            #pragma unroll
            for (int c4 = 0; c4 < 4; ++c4) {
                float4 a0 = *reinterpret_cast<const float4*>(&lds[QH + rl * 20 + (c4 << 2)]);
                float4 a1 = *reinterpret_cast<const float4*>(&lds[QH + (rl + 32) * 20 + (c4 << 2)]);
                q0[(c4<<2)+0] = a0.x; q0[(c4<<2)+1] = a0.y; q0[(c4<<2)+2] = a0.z; q0[(c4<<2)+3] = a0.w;
                q1[(c4<<2)+0] = a1.x; q1[(c4<<2)+1] = a1.y; q1[(c4<<2)+2] = a1.z; q1[(c4<<2)+3] = a1.w;
            }
            float sc0[8], sc1[8];
            #pragma unroll
            for (int ju = 0; ju < 8; ++ju) {
                float s0 = 0.f, s1 = 0.f;
                #pragma unroll
                for (int c4 = 0; c4 < 4; ++c4) {
                    const float4 kv = *reinterpret_cast<const float4*>(
                        &lds[KH + (ju * 8 + jg) * 20 + (c4 << 2)]);
                    s0 = fmaf(q0[(c4<<2)+0], kv.x, s0); s0 = fmaf(q0[(c4<<2)+1], kv.y, s0);
                    s0 = fmaf(q0[(c4<<2)+2], kv.z, s0); s0 = fmaf(q0[(c4<<2)+3], kv.w, s0);
                    s1 = fmaf(q1[(c4<<2)+0], kv.x, s1); s1 = fmaf(q1[(c4<<2)+1], kv.y, s1);
                    s1 = fmaf(q1[(c4<<2)+2], kv.z, s1); s1 = fmaf(q1[(c4<<2)+3], kv.w, s1);
                }
                sc0[ju] = s0; sc1[ju] = s1;
            }
            float m0 = -1e9f, m1 = -1e9f;
            #pragma unroll
            for (int ju = 0; ju < 8; ++ju) {
                bool mk = (mbits >> ju) & 1;
                sc0[ju] = mk ? sc0[ju] * 0.25f : -1e9f;
                sc1[ju] = mk ? sc1[ju] * 0.25f : -1e9f;
                m0 = fmaxf(m0, sc0[ju]); m1 = fmaxf(m1, sc1[ju]);
            }
            m0 = fmaxf(m0, __shfl_xor(m0, 1)); m0 = fmaxf(m0, __shfl_xor(m0, 2)); m0 = fmaxf(m0, __shfl_xor(m0, 4));
            m1 = fmaxf(m1, __shfl_xor(m1, 1)); m1 = fmaxf(m1, __shfl_xor(m1, 2)); m1 = fmaxf(m1, __shfl_xor(m1, 4));
            float z0 = 0.f, z1 = 0.f;
            float p0[8], p1[8];
            #pragma unroll
            for (int ju = 0; ju < 8; ++ju) {
                p0[ju] = __expf(sc0[ju] - m0); z0 += p0[ju];
                p1[ju] = __expf(sc1[ju] - m1); z1 += p1[ju];
            }
            z0 += __shfl_xor(z0, 1); z0 += __shfl_xor(z0, 2); z0 += __shfl_xor(z0, 4);
            z1 += __shfl_xor(z1, 1); z1 += __shfl_xor(z1, 2); z1 += __shfl_xor(z1, 4);
            float iz0 = 1.f / z0, iz1 = 1.f / z1;
            #pragma unroll
            for (int ju = 0; ju < 8; ++ju) {
                p0[ju] = p0[ju] * iz0 * g0[ju];
                p1[ju] = p1[ju] * iz1 * g1[ju];
            }
            float po0[16], po1[16];
            #pragma unroll
            for (int c = 0; c < 16; ++c) { po0[c] = 0.f; po1[c] = 0.f; }
            #pragma unroll
            for (int ju = 0; ju < 8; ++ju) {
                #pragma unroll
                for (int c4 = 0; c4 < 4; ++c4) {
                    const float4 v = *reinterpret_cast<const float4*>(
                        &lds[VH + (ju * 8 + jg) * 20 + (c4 << 2)]);
                    po0[(c4<<2)+0] = fmaf(p0[ju], v.x, po0[(c4<<2)+0]);
                    po0[(c4<<2)+1] = fmaf(p0[ju], v.y, po0[(c4<<2)+1]);
                    po0[(c4<<2)+2] = fmaf(p0[ju], v.z, po0[(c4<<2)+2]);
                    po0[(c4<<2)+3] = fmaf(p0[ju], v.w, po0[(c4<<2)+3]);
                    po1[(c4<<2)+0] = fmaf(p1[ju], v.x, po1[(c4<<2)+0]);
                    po1[(c4<<2)+1] = fmaf(p1[ju], v.y, po1[(c4<<2)+1]);
                    po1[(c4<<2)+2] = fmaf(p1[ju], v.z, po1[(c4<<2)+2]);
                    po1[(c4<<2)+3] = fmaf(p1[ju], v.w, po1[(c4<<2)+3]);
                }
            }
            #pragma unroll
            for (int c = 0; c < 16; ++c) {
                po0[c] += __shfl_xor(po0[c], 1); po0[c] += __shfl_xor(po0[c], 2); po0[c] += __shfl_xor(po0[c], 4);
                po1[c] += __shfl_xor(po1[c], 1); po1[c] += __shfl_xor(po1[c], 2); po1[c] += __shfl_xor(po1[c], 4);
            }
            __syncthreads();          // QH/KH/VH reads done
            if (jg == 0) {            // O_h overwrites QH
                #pragma unroll
                for (int c4 = 0; c4 < 4; ++c4) {
                    *reinterpret_cast<float4*>(&lds[QH + rl * 20 + (c4 << 2)]) =
                        make_float4(po0[(c4<<2)], po0[(c4<<2)+1], po0[(c4<<2)+2], po0[(c4<<2)+3]);
                    *reinterpret_cast<float4*>(&lds[QH + (rl + 32) * 20 + (c4 << 2)]) =
                        make_float4(po1[(c4<<2)], po1[(c4<<2)+1], po1[(c4<<2)+2], po1[(c4<<2)+3]);
                }
            }
            __syncthreads();
            // O-proj slice: xr += O_h @ Wo[hb:hb+16, :]
            {
                const float* Wo = aw + 12288; const float* bo = ab + 192;
                float oh[16];
                #pragma unroll
                for (int c4 = 0; c4 < 4; ++c4) {
                    float4 o4 = *reinterpret_cast<const float4*>(&lds[QH + lane * 20 + (c4 << 2)]);
                    oh[(c4<<2)+0] = o4.x; oh[(c4<<2)+1] = o4.y; oh[(c4<<2)+2] = o4.z; oh[(c4<<2)+3] = o4.w;
                }
                float acc[16];
                #pragma unroll
                for (int j = 0; j < 16; ++j) acc[j] = (hh == 0) ? bo[c0 + j] : 0.f;
                #pragma unroll
                for (int d = 0; d < 16; ++d) {
                    const float* wr = Wo + (hb + d) * 64 + c0;
                    #pragma unroll
                    for (int j = 0; j < 16; ++j) acc[j] = fmaf(oh[d], wr[j], acc[j]);
                }
                #pragma unroll
                for (int j = 0; j < 16; ++j) xr[j] += acc[j];
            }
        }

        // ---- FFN (two 64-col halves of F share one buffer) ----
        LN_STORE(l2g, l2b, lds[A + c_ * 64 + lane] = hv_);
        {   // F-lo
            float fa[16];
            #pragma unroll
            for (int j = 0; j < 16; ++j) fa[j] = fb1[c0 + j];
            #pragma unroll 8
            for (int kk = 0; kk < 64; ++kk) {
                float a = lds[A + kk * 64 + lane];
                const float* wr = fw1 + kk * 128 + c0;
                #pragma unroll
                for (int j = 0; j < 16; ++j) fa[j] = fmaf(a, wr[j], fa[j]);
            }
            #pragma unroll
            for (int j = 0; j < 16; ++j) lds[Bb + (c0 + j) * 64 + lane] = fmaxf(fa[j], 0.f);
        }
        __syncthreads();
        {   // xr += F-lo @ W2[0:64]
            float acc[16];
            #pragma unroll
            for (int j = 0; j < 16; ++j) acc[j] = fb2[c0 + j];
            #pragma unroll 8
            for (int kk = 0; kk < 64; ++kk) {
                float a = lds[Bb + kk * 64 + lane];
                const float* wr = fw2 + kk * 64 + c0;
                #pragma unroll
                for (int j = 0; j < 16; ++j) acc[j] = fmaf(a, wr[j], acc[j]);
            }
            #pragma unroll
            for (int j = 0; j < 16; ++j) xr[j] += acc[j];
        }
        __syncthreads();
        {   // F-hi
            float fa[16];
            #pragma unroll
            for (int j = 0; j < 16; ++j) fa[j] = fb1[64 + c0 + j];
            #pragma unroll 8
            for (int kk = 0; kk < 64; ++kk) {
                float a = lds[A + kk * 64 + lane];
                const float* wr = fw1 + kk * 128 + 64 + c0;
                #pragma unroll
                for (int j = 0; j < 16; ++j) fa[j] = fmaf(a, wr[j], fa[j]);
            }
            #pragma unroll
            for (int j = 0; j < 16; ++j) lds[Bb + (c0 + j) * 64 + lane] = fmaxf(fa[j], 0.f);
        }
        __syncthreads();
        {   // xr += F-hi @ W2[64:128]
            float acc[16];
            #pragma unroll
            for (int j = 0; j < 16; ++j) acc[j] = 0.f;
            #pragma unroll 8
            for (int kk = 0; kk < 64; ++kk) {
                float a = lds[Bb + kk * 64 + lane];
                const float* wr = fw2 + (64 + kk) * 64 + c0;
                #pragma unroll
                for (int j = 0; j < 16; ++j) acc[j] = fmaf(a, wr[j], acc[j]);
            }
            #pragma unroll
            for (int j = 0; j < 16; ++j) xr[j] += acc[j];
        }
        // next phase's LN barriers protect A/Bb reuse
    }

    // ================= reduction / calculator head =================
    LN_STORE(enc_g, enc_b, lds[Bb + lane * 65 + c_] = hv_);   // hR stride 65
    if (tid < 64) {       // scores = h @ red_w + red_b + (1-mask)*-1e9
        float s = 0.f;
        #pragma unroll 8
        for (int c2 = 0; c2 < 64; ++c2)
            s = fmaf(lds[Bb + tid * 65 + c2], red_w[c2], s);
        s += red_b[0];
        s += (1.f - lds[M_MASK + tid]) * -1e9f;
        lds[M_SU + tid] = s;
    }
    __syncthreads();

    if (wv == 0) {        // softmax, scans, digit assembly (wave 0)
        float s = lds[M_SU + lane];
        float m = s;
        #pragma unroll
        for (int off = 1; off < 64; off <<= 1) m = fmaxf(m, __shfl_xor(m, off));
        float ee = expf(s - m);
        float z = ee;
        #pragma unroll
        for (int off = 1; off < 64; off <<= 1) z += __shfl_xor(z, off);
        float rw = ee / z;
        lds[M_SD + lane] = rw;
        float cum = rw;
        #pragma unroll
        for (int off = 1; off < 64; off <<= 1) { float t2 = __shfl_up(cum, off); if (lane >= off) cum += t2; }
        float isd = lds[M_ISD + lane], dvv = lds[M_DVAL + lane];
        float lm = (1.f - cum) * isd;
        float rm = (cum - rw) * isd;
        float cl = lm;
        #pragma unroll
        for (int off = 1; off < 64; off <<= 1) { float t2 = __shfl_up(cl, off); if (lane >= off) cl += t2; }
        float totl = __shfl(cl, 63);
        float wL = powf(10.f, (totl - cl) * lm) * lm;
        float lv = dvv * wL;
        #pragma unroll
        for (int off = 1; off < 64; off <<= 1) lv += __shfl_xor(lv, off);
        float cr = rm;
        #pragma unroll
        for (int off = 1; off < 64; off <<= 1) { float t2 = __shfl_up(cr, off); if (lane >= off) cr += t2; }
        float totr = __shfl(cr, 63);
        float wR = powf(10.f, (totr - cr) * rm) * rm;
        float rv = dvv * wR;
        #pragma unroll
        for (int off = 1; off < 64; off <<= 1) rv += __shfl_xor(rv, off);
        if (lane == 0) { lds[M_DG + 2] = lv; lds[M_DG + 3] = rv; }
    }
    __syncthreads();

    if (tid < 64) {       // pooled[c] = sum_r h[r][c] * rw[r]
        float p = 0.f;
        #pragma unroll 8
        for (int r2 = 0; r2 < 64; ++r2)
            p = fmaf(lds[Bb + r2 * 65 + tid], lds[M_SD + r2], p);
        lds[M_NBU + tid] = p;
    }
    __syncthreads();
    if (tid < 4) {        // op logits
        float s = opc_b[tid];
        for (int c2 = 0; c2 < 64; ++c2) s = fmaf(lds[M_NBU + c2], opc_w[(c2 << 2) + tid], s);
        lds[M_DG + 4 + tid] = s;
    }
    __syncthreads();
    if (tid == 0) {       // hard argmax op select + fixed ops
        float l = lds[M_DG + 2], r = lds[M_DG + 3];
        float o0 = lds[M_DG + 4], o1 = lds[M_DG + 5], o2 = lds[M_DG + 6], o3 = lds[M_DG + 7];
        int op = 0; float bm = o0;
        if (o1 > bm) { bm = o1; op = 1; }
        if (o2 > bm) { bm = o2; op = 2; }
        if (o3 > bm) { bm = o3; op = 3; }
        float res, vl = 1.f;
        if (op == 0)      res = l + r;
        else if (op == 1) res = l - r;
        else if (op == 2) res = l * r;
        else { bool bad = fabsf(r) < 1e-6f; res = bad ? 0.f : (l / r); vl = bad ? 0.f : 1.f; }
        float rc = (res > 0.f) ? log1pf(res) : ((res < 0.f) ? -log1pf(-res) : 0.f);
        lds[M_DG + 0] = rc; lds[M_DG + 1] = vl;
        out[O_RES + b]   = res;
        out[O_VALID + b] = vl;
        out[O_LEFT + b]  = l;
        out[O_RIGHT + b] = r;
    }
    __syncthreads();
    if (tid < 64) {
        float rc = lds[M_DG + 0], vl = lds[M_DG + 1];
        out[O_REMB + (b << 6) + tid] = rc * res_w[tid] + vl * res_w[64 + tid] + res_b[tid];
        out[O_RW + (b << 6) + tid] = lds[M_SD + tid];
    }
    if (tid >= 64 && tid < 68) {
        int o = tid - 64;
        out[O_OPL + (b << 2) + o] = lds[M_DG + 4 + o];
    }
}

extern "C" void kernel_launch(void* const* d_in, const int* in_sizes, int n_in,
                              void* d_out, int out_size, void* d_ws, size_t ws_size,
                              hipStream_t stream)
{
    fsa_kernel<<<dim3(BATCH), dim3(256), 0, stream>>>(
        (const int*)d_in[0],
        (const float*)d_in[1],  (const float*)d_in[2],  (const float*)d_in[3],
        (const float*)d_in[4],  (const float*)d_in[5],  (const float*)d_in[6],  (const float*)d_in[7],
        (const float*)d_in[8],  (const float*)d_in[9],  (const float*)d_in[10], (const float*)d_in[11],
        (const float*)d_in[12], (const float*)d_in[13], (const float*)d_in[14], (const float*)d_in[15],
        (const float*)d_in[16], (const float*)d_in[17], (const float*)d_in[18], (const float*)d_in[19],
        (const float*)d_in[20], (const float*)d_in[21], (const float*)d_in[22], (const float*)d_in[23],
        (const float*)d_in[24], (const float*)d_in[25], (const float*)d_in[26], (const float*)d_in[27],
        (float*)d_out);
}

// Round 9
// 1298.478 us; speedup vs baseline: 1.5277x; 1.1014x over previous
//
#include <hip/hip_runtime.h>
#include <math.h>

// B=4096, L=64, H=64, V=21, NH=4, HD=16, FF=128, NL=2
constexpr int BATCH = 4096;

// ---------------- LDS regions (float indices), total 63,488 B -> 2 blocks/CU
// A  [0,4352):      hT [c][r] stride 64 / gK^T s64 / O rows s65
// Bb [4352,14592):  gQ^T s64 / F s64 / hR s65 / per-head K,V (4 x {64x20,64x20})
// M  [14592,15872): masks, scan state, LN partials
constexpr int A    = 0;
constexpr int Bb   = 4352;
constexpr int KV   = 4352;          // K_h = KV + wv*2560, V_h = K_h + 1280
constexpr int MB   = 14592;
constexpr int M_MASK = MB + 0;
constexpr int M_DVAL = MB + 64;
constexpr int M_ISD  = MB + 128;
constexpr int M_SD   = MB + 192;    // final rw
constexpr int M_NBU  = MB + 256;    // pooled
constexpr int M_DG   = MB + 320;    // scalars
constexpr int M_DVEC = MB + 384;    // g diagonal
constexpr int M_S    = MB + 448;    // prefix sums
constexpr int M_PRU  = MB + 512;    // prior g[i,i+1]
constexpr int M_PRD  = MB + 576;    // prior g[i,i]
constexpr int M_SU   = MB + 640;    // s_up
constexpr int M_SDN  = MB + 704;    // s_dn
constexpr int PS     = MB + 768;    // 4x64 LN partial sums
constexpr int PSQ    = MB + 1024;   // 4x64 LN partial sumsq
constexpr int LDSN   = MB + 1280;   // 15872 floats = 63,488 B

// ---------------- output layout (floats) ----------------
constexpr int O_RES   = 0;
constexpr int O_REMB  = 4096;
constexpr int O_VALID = 266240;
constexpr int O_LEFT  = 270336;
constexpr int O_RIGHT = 274432;
constexpr int O_OPL   = 278528;
constexpr int O_RW    = 294912;

// LN of xr; stats via 4-wave LDS partial reduce; then STORE per column.
#define LN_STORE(GPTR, BPTR, STORE) do {                                  \
    float s_ = 0.f, q_ = 0.f;                                             \
    _Pragma("unroll") for (int j = 0; j < 16; ++j) {                      \
        s_ += xr[j]; q_ = fmaf(xr[j], xr[j], q_); }                       \
    lds[PS  + (wv << 6) + lane] = s_;                                     \
    lds[PSQ + (wv << 6) + lane] = q_;                                     \
    __syncthreads();                                                      \
    float fs_ = lds[PS + lane] + lds[PS + 64 + lane]                      \
              + lds[PS + 128 + lane] + lds[PS + 192 + lane];              \
    float fq_ = lds[PSQ + lane] + lds[PSQ + 64 + lane]                    \
              + lds[PSQ + 128 + lane] + lds[PSQ + 192 + lane];            \
    float mu_ = fs_ * 0.015625f;                                          \
    float inv_ = rsqrtf(fq_ * 0.015625f - mu_ * mu_ + 1e-6f);             \
    _Pragma("unroll") for (int j = 0; j < 16; ++j) {                      \
        int c_ = c0 + j;                                                  \
        float hv_ = (xr[j] - mu_) * inv_ * (GPTR)[c_] + (BPTR)[c_];       \
        STORE;                                                            \
    }                                                                     \
    __syncthreads();                                                      \
} while (0)

__global__ void __launch_bounds__(256, 2) fsa_kernel(
    const int* __restrict__ tok,
    const float* __restrict__ emb, const float* __restrict__ np_w, const float* __restrict__ np_b,
    const float* __restrict__ grp_wq, const float* __restrict__ grp_bq,
    const float* __restrict__ grp_wk, const float* __restrict__ grp_bk,
    const float* __restrict__ grp_ln_g, const float* __restrict__ grp_ln_b,
    const float* __restrict__ attn_w, const float* __restrict__ attn_b,
    const float* __restrict__ ln1_g, const float* __restrict__ ln1_b,
    const float* __restrict__ ln2_g, const float* __restrict__ ln2_b,
    const float* __restrict__ ffn_w1, const float* __restrict__ ffn_b1,
    const float* __restrict__ ffn_w2, const float* __restrict__ ffn_b2,
    const float* __restrict__ enc_g, const float* __restrict__ enc_b,
    const float* __restrict__ red_w, const float* __restrict__ red_b,
    const float* __restrict__ opc_w, const float* __restrict__ opc_b,
    const float* __restrict__ res_w, const float* __restrict__ res_b,
    float* __restrict__ out)
{
    __shared__ __align__(16) float lds[LDSN];
    const int b = blockIdx.x;
    const int tid = threadIdx.x;
    const int lane = tid & 63;
    const int wv = __builtin_amdgcn_readfirstlane(tid >> 6);
    const int c0 = wv << 4;
    float xr[16];                 // x[lane][c0 .. c0+15] in registers

    // ================= embedding + positional encoding =================
    {
        int t = tok[(b << 6) + lane];
        float mk  = (t != 0) ? 1.f : 0.f;
        float isd = (t >= 4 && t <= 13) ? 1.f : 0.f;
        float dvv = ((float)t - 4.f) * isd;
        float iso = (t >= 14 && t <= 17) ? 1.f : 0.f;
        float opt = iso * ((float)t - 13.f);
        if (wv == 0) {
            lds[M_MASK + lane] = mk;  lds[M_DVAL + lane] = dvv; lds[M_ISD + lane] = isd;
            lds[M_PRU + lane] = 0.f;  lds[M_PRD + lane] = 0.f;
        }
        const float lg = -0.143911568f;   // -ln(10000)/64
        #pragma unroll
        for (int j = 0; j < 16; ++j) {
            int c = c0 + j;
            float freq = expf((float)(c & ~1) * lg);
            float ang = (float)lane * freq;
            float pe = (c & 1) ? cosf(ang) : sinf(ang);
            xr[j] = emb[t * 64 + c] * 8.f
                  + dvv * np_w[c] + isd * np_w[64 + c]
                  + opt * np_w[128 + c] + iso * np_w[192 + c]
                  + np_b[c] + pe;
        }
    }
    __syncthreads();
    // 64-bit pairmask register (bit j = mask[j] > 0), same in every lane
    const unsigned long long mall = __ballot(lds[M_MASK + lane] > 0.f);

    // ================= transformer layers =================
    for (int il = 0; il < 2; ++il) {
        const float* gwq = grp_wq + il * 4096; const float* gbq = grp_bq + (il << 6);
        const float* gwk = grp_wk + il * 4096; const float* gbk = grp_bk + (il << 6);
        const float* glg = grp_ln_g + (il << 6); const float* glb = grp_ln_b + (il << 6);
        const float* aw  = attn_w + il * 16384;  const float* ab  = attn_b + (il << 8);
        const float* l1g = ln1_g + (il << 6);    const float* l1b = ln1_b + (il << 6);
        const float* l2g = ln2_g + (il << 6);    const float* l2b = ln2_b + (il << 6);
        const float* fw1 = ffn_w1 + il * 8192;   const float* fb1 = ffn_b1 + (il << 7);
        const float* fw2 = ffn_w2 + il * 8192;   const float* fb2 = ffn_b2 + (il << 6);

        // ---- group (constituent) attention ----
        LN_STORE(glg, glb, lds[A + c_ * 64 + lane] = hv_);
        {   // fused gQ/gK GEMM streaming hT
            float qa[16], ka[16];
            #pragma unroll
            for (int j = 0; j < 16; ++j) { qa[j] = gbq[c0 + j]; ka[j] = gbk[c0 + j]; }
            #pragma unroll 8
            for (int kk = 0; kk < 64; ++kk) {
                float a = lds[A + kk * 64 + lane];
                const float* wq = gwq + kk * 64 + c0;
                const float* wk = gwk + kk * 64 + c0;
                #pragma unroll
                for (int j = 0; j < 16; ++j) {
                    qa[j] = fmaf(a, wq[j], qa[j]);
                    ka[j] = fmaf(a, wk[j], ka[j]);
                }
            }
            #pragma unroll
            for (int j = 0; j < 16; ++j) lds[Bb + (c0 + j) * 64 + lane] = qa[j]; // gQ^T
            __syncthreads();          // hT reads done; gQ^T visible
            #pragma unroll
            for (int j = 0; j < 16; ++j) lds[A + (c0 + j) * 64 + lane] = ka[j];  // gK^T
            __syncthreads();
        }

        if (tid < 126) {              // s[i,i+1] and s[i+1,i]
            int i = tid >> 1, w = tid & 1;
            int ra = w ? i + 1 : i, rb = w ? i : i + 1;
            float s = 0.f;
            #pragma unroll 8
            for (int c2 = 0; c2 < 64; ++c2)
                s = fmaf(lds[Bb + c2 * 64 + ra], lds[A + c2 * 64 + rb], s);
            lds[(w ? M_SDN : M_SU) + i] = s * 0.125f;   // / sqrt(H)
        }
        __syncthreads();

        if (wv == 0) {   // merged: masked softmax + symmetrize + prior + shfl scan
            const int i = lane;
            float mi  = lds[M_MASK + i];
            float mup = (i < 63) ? lds[M_MASK + i + 1] : 0.f;
            float mdn = (i > 0)  ? lds[M_MASK + i - 1] : 0.f;
            float eu = (mi > 0.f && mup > 0.f) ? lds[M_SU + i] : -1e9f;
            float ed = (i > 0 && mi > 0.f && mdn > 0.f) ? lds[M_SDN + i - 1] : -1e9f;
            float m = fmaxf(eu, ed);
            float nu, nd, ng;
            if (m <= -1e9f) { nu = 0.015625f; nd = 0.015625f; ng = 0.015625f; }
            else {
                float zu = __expf(eu - m), zd = __expf(ed - m);
                float iz = 1.f / (zu + zd);
                nu = zu * iz; nd = zd * iz; ng = 0.f;
            }
            float nd1 = __shfl_down(nd, 1);       // nb_dn of row i+1
            float pd = lds[M_PRD + i];
            float dsym = sqrtf(ng * ng + 1e-9f);
            float d2 = pd + (1.f - pd) * dsym;
            lds[M_DVEC + i] = d2; lds[M_PRD + i] = d2;
            float la = 0.f;
            if (i < 63) {
                float pu = lds[M_PRU + i];
                float as_ = sqrtf(nu * nd1 + 1e-9f);
                float a2 = pu + (1.f - pu) * as_;
                la = logf(a2 + 1e-9f);
                lds[M_PRU + i] = __expf(la) + 1e-9f;   // next-layer prior
            }
            float x = __shfl_up(la, 1);
            if (i == 0) x = 0.f;
            #pragma unroll
            for (int off = 1; off < 64; off <<= 1) {
                float t2 = __shfl_up(x, off);
                if (i >= off) x += t2;
            }
            lds[M_S + i] = x;                     // S[i] = sum_{k<i} la[k]
        }
        __syncthreads();

        // ---- multi-head attention: wave wv owns head wv; lane owns row=lane ----
        LN_STORE(l1g, l1b, lds[A + c_ * 64 + lane] = hv_);
        {
            const int hb = wv << 4;
            const int KVb = KV + wv * 2560;
            // fused per-head Q/K/V GEMM (48 FMA per h element)
            float qa[16], ka[16], va[16];
            #pragma unroll
            for (int j = 0; j < 16; ++j) {
                qa[j] = ab[hb + j]; ka[j] = ab[64 + hb + j]; va[j] = ab[128 + hb + j];
            }
            #pragma unroll 4
            for (int kk = 0; kk < 64; ++kk) {
                float a = lds[A + kk * 64 + lane];
                const float* wq  = aw + kk * 64 + hb;
                const float* wk  = aw + 4096 + kk * 64 + hb;
                const float* wvp = aw + 8192 + kk * 64 + hb;
                #pragma unroll
                for (int j = 0; j < 16; ++j) {
                    qa[j] = fmaf(a, wq[j], qa[j]);
                    ka[j] = fmaf(a, wk[j], ka[j]);
                    va[j] = fmaf(a, wvp[j], va[j]);
                }
            }
            // K,V to own head slice (wave-internal; no __syncthreads needed)
            #pragma unroll
            for (int c4 = 0; c4 < 4; ++c4) {
                *reinterpret_cast<float4*>(&lds[KVb + lane * 20 + (c4 << 2)]) =
                    make_float4(ka[(c4<<2)], ka[(c4<<2)+1], ka[(c4<<2)+2], ka[(c4<<2)+3]);
                *reinterpret_cast<float4*>(&lds[KVb + 1280 + lane * 20 + (c4 << 2)]) =
                    make_float4(va[(c4<<2)], va[(c4<<2)+1], va[(c4<<2)+2], va[(c4<<2)+3]);
            }
            // flash-style online softmax over j tiles; K/V reads are broadcasts
            float Sr  = lds[M_S + lane];
            float dvr = lds[M_DVEC + lane];
            float o[16];
            #pragma unroll
            for (int c = 0; c < 16; ++c) o[c] = 0.f;
            float mrun = -1e30f, z = 0.f;
            #pragma unroll
            for (int jt = 0; jt < 8; ++jt) {
                float sc[8]; float tm = -1e30f;
                #pragma unroll
                for (int jj = 0; jj < 8; ++jj) {
                    const int j = (jt << 3) + jj;
                    float s = 0.f;
                    #pragma unroll
                    for (int c4 = 0; c4 < 4; ++c4) {
                        const float4 kv = *reinterpret_cast<const float4*>(
                            &lds[KVb + j * 20 + (c4 << 2)]);
                        s = fmaf(qa[(c4<<2)+0], kv.x, s); s = fmaf(qa[(c4<<2)+1], kv.y, s);
                        s = fmaf(qa[(c4<<2)+2], kv.z, s); s = fmaf(qa[(c4<<2)+3], kv.w, s);
                    }
                    s = ((mall >> j) & 1ull) ? s * 0.25f : -1e9f;
                    sc[jj] = s; tm = fmaxf(tm, s);
                }
                float mn = fmaxf(mrun, tm);
                float rs = __expf(mrun - mn);
                z *= rs;
                #pragma unroll
                for (int c = 0; c < 16; ++c) o[c] *= rs;
                mrun = mn;
                #pragma unroll
                for (int jj = 0; jj < 8; ++jj) {
                    const int j = (jt << 3) + jj;
                    float e = __expf(sc[jj] - mn);
                    z += e;
                    float Sj = lds[M_S + j];
                    float g = (j == lane) ? dvr
                              : (__expf((j > lane) ? (Sj - Sr) : (Sr - Sj)) + 1e-9f);
                    float w = e * g;
                    #pragma unroll
                    for (int c4 = 0; c4 < 4; ++c4) {
                        const float4 vv = *reinterpret_cast<const float4*>(
                            &lds[KVb + 1280 + j * 20 + (c4 << 2)]);
                        o[(c4<<2)+0] = fmaf(w, vv.x, o[(c4<<2)+0]);
                        o[(c4<<2)+1] = fmaf(w, vv.y, o[(c4<<2)+1]);
                        o[(c4<<2)+2] = fmaf(w, vv.z, o[(c4<<2)+2]);
                        o[(c4<<2)+3] = fmaf(w, vv.w, o[(c4<<2)+3]);
                    }
                }
            }
            float iz = 1.f / z;
            __syncthreads();          // everyone's h reads done before O overwrites A
            #pragma unroll
            for (int c = 0; c < 16; ++c) lds[A + lane * 65 + hb + c] = o[c] * iz;
            __syncthreads();
            // O-proj: xr += O @ Wo + bo (O rows stride 65, 2-way free)
            const float* Wo = aw + 12288; const float* bo = ab + 192;
            float acc[16];
            #pragma unroll
            for (int j = 0; j < 16; ++j) acc[j] = bo[c0 + j];
            #pragma unroll 8
            for (int dd = 0; dd < 64; ++dd) {
                float a = lds[A + lane * 65 + dd];
                const float* wr = Wo + dd * 64 + c0;
                #pragma unroll
                for (int j = 0; j < 16; ++j) acc[j] = fmaf(a, wr[j], acc[j]);
            }
            #pragma unroll
            for (int j = 0; j < 16; ++j) xr[j] += acc[j];
        }
        __syncthreads();              // O reads done before FFN's LN overwrites A

        // ---- FFN (two 64-col halves of F share one buffer) ----
        LN_STORE(l2g, l2b, lds[A + c_ * 64 + lane] = hv_);
        {   // F-lo
            float fa[16];
            #pragma unroll
            for (int j = 0; j < 16; ++j) fa[j] = fb1[c0 + j];
            #pragma unroll 8
            for (int kk = 0; kk < 64; ++kk) {
                float a = lds[A + kk * 64 + lane];
                const float* wr = fw1 + kk * 128 + c0;
                #pragma unroll
                for (int j = 0; j < 16; ++j) fa[j] = fmaf(a, wr[j], fa[j]);
            }
            #pragma unroll
            for (int j = 0; j < 16; ++j) lds[Bb + (c0 + j) * 64 + lane] = fmaxf(fa[j], 0.f);
        }
        __syncthreads();
        {   // xr += F-lo @ W2[0:64]
            float acc[16];
            #pragma unroll
            for (int j = 0; j < 16; ++j) acc[j] = fb2[c0 + j];
            #pragma unroll 8
            for (int kk = 0; kk < 64; ++kk) {
                float a = lds[Bb + kk * 64 + lane];
                const float* wr = fw2 + kk * 64 + c0;
                #pragma unroll
                for (int j = 0; j < 16; ++j) acc[j] = fmaf(a, wr[j], acc[j]);
            }
            #pragma unroll
            for (int j = 0; j < 16; ++j) xr[j] += acc[j];
        }
        __syncthreads();
        {   // F-hi
            float fa[16];
            #pragma unroll
            for (int j = 0; j < 16; ++j) fa[j] = fb1[64 + c0 + j];
            #pragma unroll 8
            for (int kk = 0; kk < 64; ++kk) {
                float a = lds[A + kk * 64 + lane];
                const float* wr = fw1 + kk * 128 + 64 + c0;
                #pragma unroll
                for (int j = 0; j < 16; ++j) fa[j] = fmaf(a, wr[j], fa[j]);
            }
            #pragma unroll
            for (int j = 0; j < 16; ++j) lds[Bb + (c0 + j) * 64 + lane] = fmaxf(fa[j], 0.f);
        }
        __syncthreads();
        {   // xr += F-hi @ W2[64:128]
            float acc[16];
            #pragma unroll
            for (int j = 0; j < 16; ++j) acc[j] = 0.f;
            #pragma unroll 8
            for (int kk = 0; kk < 64; ++kk) {
                float a = lds[Bb + kk * 64 + lane];
                const float* wr = fw2 + (64 + kk) * 64 + c0;
                #pragma unroll
                for (int j = 0; j < 16; ++j) acc[j] = fmaf(a, wr[j], acc[j]);
            }
            #pragma unroll
            for (int j = 0; j < 16; ++j) xr[j] += acc[j];
        }
        // next phase's LN barriers protect A/Bb reuse
    }

    // ================= reduction / calculator head =================
    LN_STORE(enc_g, enc_b, lds[Bb + lane * 65 + c_] = hv_);   // hR stride 65
    if (tid < 64) {       // scores = h @ red_w + red_b + (1-mask)*-1e9
        float s = 0.f;
        #pragma unroll 8
        for (int c2 = 0; c2 < 64; ++c2)
            s = fmaf(lds[Bb + tid * 65 + c2], red_w[c2], s);
        s += red_b[0];
        s += (1.f - lds[M_MASK + tid]) * -1e9f;
        lds[M_SU + tid] = s;
    }
    __syncthreads();

    if (wv == 0) {        // softmax, scans, digit assembly (wave 0)
        float s = lds[M_SU + lane];
        float m = s;
        #pragma unroll
        for (int off = 1; off < 64; off <<= 1) m = fmaxf(m, __shfl_xor(m, off));
        float ee = expf(s - m);
        float z = ee;
        #pragma unroll
        for (int off = 1; off < 64; off <<= 1) z += __shfl_xor(z, off);
        float rw = ee / z;
        lds[M_SD + lane] = rw;
        float cum = rw;
        #pragma unroll
        for (int off = 1; off < 64; off <<= 1) { float t2 = __shfl_up(cum, off); if (lane >= off) cum += t2; }
        float isd = lds[M_ISD + lane], dvv = lds[M_DVAL + lane];
        float lm = (1.f - cum) * isd;
        float rm = (cum - rw) * isd;
        float cl = lm;
        #pragma unroll
        for (int off = 1; off < 64; off <<= 1) { float t2 = __shfl_up(cl, off); if (lane >= off) cl += t2; }
        float totl = __shfl(cl, 63);
        float wL = powf(10.f, (totl - cl) * lm) * lm;
        float lv = dvv * wL;
        #pragma unroll
        for (int off = 1; off < 64; off <<= 1) lv += __shfl_xor(lv, off);
        float cr = rm;
        #pragma unroll
        for (int off = 1; off < 64; off <<= 1) { float t2 = __shfl_up(cr, off); if (lane >= off) cr += t2; }
        float totr = __shfl(cr, 63);
        float wR = powf(10.f, (totr - cr) * rm) * rm;
        float rv = dvv * wR;
        #pragma unroll
        for (int off = 1; off < 64; off <<= 1) rv += __shfl_xor(rv, off);
        if (lane == 0) { lds[M_DG + 2] = lv; lds[M_DG + 3] = rv; }
    }
    __syncthreads();

    if (tid < 64) {       // pooled[c] = sum_r h[r][c] * rw[r]
        float p = 0.f;
        #pragma unroll 8
        for (int r2 = 0; r2 < 64; ++r2)
            p = fmaf(lds[Bb + r2 * 65 + tid], lds[M_SD + r2], p);
        lds[M_NBU + tid] = p;
    }
    __syncthreads();
    if (tid < 4) {        // op logits
        float s = opc_b[tid];
        for (int c2 = 0; c2 < 64; ++c2) s = fmaf(lds[M_NBU + c2], opc_w[(c2 << 2) + tid], s);
        lds[M_DG + 4 + tid] = s;
    }
    __syncthreads();
    if (tid == 0) {       // hard argmax op select + fixed ops
        float l = lds[M_DG + 2], r = lds[M_DG + 3];
        float o0 = lds[M_DG + 4], o1 = lds[M_DG + 5], o2 = lds[M_DG + 6], o3 = lds[M_DG + 7];
        int op = 0; float bm = o0;
        if (o1 > bm) { bm = o1; op = 1; }
        if (o2 > bm) { bm = o2; op = 2; }
        if (o3 > bm) { bm = o3; op = 3; }
        float res, vl = 1.f;
        if (op == 0)      res = l + r;
        else if (op == 1) res = l - r;
        else if (op == 2) res = l * r;
        else { bool bad = fabsf(r) < 1e-6f; res = bad ? 0.f : (l / r); vl = bad ? 0.f : 1.f; }
        float rc = (res > 0.f) ? log1pf(res) : ((res < 0.f) ? -log1pf(-res) : 0.f);
        lds[M_DG + 0] = rc; lds[M_DG + 1] = vl;
        out[O_RES + b]   = res;
        out[O_VALID + b] = vl;
        out[O_LEFT + b]  = l;
        out[O_RIGHT + b] = r;
    }
    __syncthreads();
    if (tid < 64) {
        float rc = lds[M_DG + 0], vl = lds[M_DG + 1];
        out[O_REMB + (b << 6) + tid] = rc * res_w[tid] + vl * res_w[64 + tid] + res_b[tid];
        out[O_RW + (b << 6) + tid] = lds[M_SD + tid];
    }
    if (tid >= 64 && tid < 68) {
        int o = tid - 64;
        out[O_OPL + (b << 2) + o] = lds[M_DG + 4 + o];
    }
}

extern "C" void kernel_launch(void* const* d_in, const int* in_sizes, int n_in,
                              void* d_out, int out_size, void* d_ws, size_t ws_size,
                              hipStream_t stream)
{
    fsa_kernel<<<dim3(BATCH), dim3(256), 0, stream>>>(
        (const int*)d_in[0],
        (const float*)d_in[1],  (const float*)d_in[2],  (const float*)d_in[3],
        (const float*)d_in[4],  (const float*)d_in[5],  (const float*)d_in[6],  (const float*)d_in[7],
        (const float*)d_in[8],  (const float*)d_in[9],  (const float*)d_in[10], (const float*)d_in[11],
        (const float*)d_in[12], (const float*)d_in[13], (const float*)d_in[14], (const float*)d_in[15],
        (const float*)d_in[16], (const float*)d_in[17], (const float*)d_in[18], (const float*)d_in[19],
        (const float*)d_in[20], (const float*)d_in[21], (const float*)d_in[22], (const float*)d_in[23],
        (const float*)d_in[24], (const float*)d_in[25], (const float*)d_in[26], (const float*)d_in[27],
        (float*)d_out);
}

// Round 10
// 948.986 us; speedup vs baseline: 2.0904x; 1.3683x over previous
//
#include <hip/hip_runtime.h>
#include <math.h>

// B=4096, L=64, H=64, V=21, NH=4, HD=16, FF=128, NL=2
constexpr int BATCH = 4096;

// ---------------- LDS regions (float indices), total 39,168 B -> 4 blocks/CU
// A  [0,4352):      hT [c][r] stride 64 / gK^T s64 / O rows s65
// B0 [4352,9024):   PS/PSQ (512) | gQ^T s64 / F s64 (4096) | per-wave KV tiles
//                   (wv*640: K 16x20, V 16x20) | final hR at B0+512 stride 65
// M  [9024,9792):   masks, scan state
constexpr int A    = 0;
constexpr int B0   = 4352;
constexpr int PS   = B0;            // 4x64 LN partial sums
constexpr int PSQ  = B0 + 256;      // 4x64 LN partial sumsq
constexpr int BH   = B0 + 512;      // final hR, 64x65
constexpr int MB   = 9024;
constexpr int M_MASK = MB + 0;
constexpr int M_DVAL = MB + 64;
constexpr int M_ISD  = MB + 128;
constexpr int M_SD   = MB + 192;    // final rw
constexpr int M_NBU  = MB + 256;    // pooled
constexpr int M_DG   = MB + 320;    // scalars
constexpr int M_DVEC = MB + 384;    // g diagonal
constexpr int M_S    = MB + 448;    // prefix sums
constexpr int M_PRU  = MB + 512;    // prior g[i,i+1]
constexpr int M_PRD  = MB + 576;    // prior g[i,i]
constexpr int M_SU   = MB + 640;    // s_up
constexpr int M_SDN  = MB + 704;    // s_dn
constexpr int LDSN   = MB + 768;    // 9792 floats = 39,168 B

// ---------------- output layout (floats) ----------------
constexpr int O_RES   = 0;
constexpr int O_REMB  = 4096;
constexpr int O_VALID = 266240;
constexpr int O_LEFT  = 270336;
constexpr int O_RIGHT = 274432;
constexpr int O_OPL   = 278528;
constexpr int O_RW    = 294912;

// LN of xr; stats via 4-wave LDS partial reduce; then STORE per column.
#define LN_STORE(GPTR, BPTR, STORE) do {                                  \
    float s_ = 0.f, q_ = 0.f;                                             \
    _Pragma("unroll") for (int j = 0; j < 16; ++j) {                      \
        s_ += xr[j]; q_ = fmaf(xr[j], xr[j], q_); }                       \
    lds[PS  + (wv << 6) + lane] = s_;                                     \
    lds[PSQ + (wv << 6) + lane] = q_;                                     \
    __syncthreads();                                                      \
    float fs_ = lds[PS + lane] + lds[PS + 64 + lane]                      \
              + lds[PS + 128 + lane] + lds[PS + 192 + lane];              \
    float fq_ = lds[PSQ + lane] + lds[PSQ + 64 + lane]                    \
              + lds[PSQ + 128 + lane] + lds[PSQ + 192 + lane];            \
    float mu_ = fs_ * 0.015625f;                                          \
    float inv_ = rsqrtf(fq_ * 0.015625f - mu_ * mu_ + 1e-6f);             \
    _Pragma("unroll") for (int j = 0; j < 16; ++j) {                      \
        int c_ = c0 + j;                                                  \
        float hv_ = (xr[j] - mu_) * inv_ * (GPTR)[c_] + (BPTR)[c_];       \
        STORE;                                                            \
    }                                                                     \
    __syncthreads();                                                      \
} while (0)

__global__ void __launch_bounds__(256, 4) fsa_kernel(
    const int* __restrict__ tok,
    const float* __restrict__ emb, const float* __restrict__ np_w, const float* __restrict__ np_b,
    const float* __restrict__ grp_wq, const float* __restrict__ grp_bq,
    const float* __restrict__ grp_wk, const float* __restrict__ grp_bk,
    const float* __restrict__ grp_ln_g, const float* __restrict__ grp_ln_b,
    const float* __restrict__ attn_w, const float* __restrict__ attn_b,
    const float* __restrict__ ln1_g, const float* __restrict__ ln1_b,
    const float* __restrict__ ln2_g, const float* __restrict__ ln2_b,
    const float* __restrict__ ffn_w1, const float* __restrict__ ffn_b1,
    const float* __restrict__ ffn_w2, const float* __restrict__ ffn_b2,
    const float* __restrict__ enc_g, const float* __restrict__ enc_b,
    const float* __restrict__ red_w, const float* __restrict__ red_b,
    const float* __restrict__ opc_w, const float* __restrict__ opc_b,
    const float* __restrict__ res_w, const float* __restrict__ res_b,
    float* __restrict__ out)
{
    __shared__ __align__(16) float lds[LDSN];
    const int b = blockIdx.x;
    const int tid = threadIdx.x;
    const int lane = tid & 63;
    const int wv = __builtin_amdgcn_readfirstlane(tid >> 6);
    const int c0 = wv << 4;
    float xr[16];                 // x[lane][c0 .. c0+15] in registers

    // ================= embedding + positional encoding =================
    {
        int t = tok[(b << 6) + lane];
        float mk  = (t != 0) ? 1.f : 0.f;
        float isd = (t >= 4 && t <= 13) ? 1.f : 0.f;
        float dvv = ((float)t - 4.f) * isd;
        float iso = (t >= 14 && t <= 17) ? 1.f : 0.f;
        float opt = iso * ((float)t - 13.f);
        if (wv == 0) {
            lds[M_MASK + lane] = mk;  lds[M_DVAL + lane] = dvv; lds[M_ISD + lane] = isd;
            lds[M_PRU + lane] = 0.f;  lds[M_PRD + lane] = 0.f;
        }
        const float lg = -0.143911568f;   // -ln(10000)/64
        #pragma unroll
        for (int j = 0; j < 16; ++j) {
            int c = c0 + j;
            float freq = expf((float)(c & ~1) * lg);
            float ang = (float)lane * freq;
            float pe = (c & 1) ? cosf(ang) : sinf(ang);
            xr[j] = emb[t * 64 + c] * 8.f
                  + dvv * np_w[c] + isd * np_w[64 + c]
                  + opt * np_w[128 + c] + iso * np_w[192 + c]
                  + np_b[c] + pe;
        }
    }
    __syncthreads();
    // 64-bit pairmask register (bit j = mask[j] > 0), wave-uniform (SGPRs)
    const unsigned long long mall = __ballot(lds[M_MASK + lane] > 0.f);

    // ================= transformer layers =================
    for (int il = 0; il < 2; ++il) {
        const float* gwq = grp_wq + il * 4096; const float* gbq = grp_bq + (il << 6);
        const float* gwk = grp_wk + il * 4096; const float* gbk = grp_bk + (il << 6);
        const float* glg = grp_ln_g + (il << 6); const float* glb = grp_ln_b + (il << 6);
        const float* aw  = attn_w + il * 16384;  const float* ab  = attn_b + (il << 8);
        const float* l1g = ln1_g + (il << 6);    const float* l1b = ln1_b + (il << 6);
        const float* l2g = ln2_g + (il << 6);    const float* l2b = ln2_b + (il << 6);
        const float* fw1 = ffn_w1 + il * 8192;   const float* fb1 = ffn_b1 + (il << 7);
        const float* fw2 = ffn_w2 + il * 8192;   const float* fb2 = ffn_b2 + (il << 6);

        // ---- group (constituent) attention ----
        LN_STORE(glg, glb, lds[A + c_ * 64 + lane] = hv_);
        {   // fused gQ/gK GEMM streaming hT
            float qa[16], ka[16];
            #pragma unroll
            for (int j = 0; j < 16; ++j) { qa[j] = gbq[c0 + j]; ka[j] = gbk[c0 + j]; }
            #pragma unroll 8
            for (int kk = 0; kk < 64; ++kk) {
                float a = lds[A + kk * 64 + lane];
                const float* wq = gwq + kk * 64 + c0;
                const float* wk = gwk + kk * 64 + c0;
                #pragma unroll
                for (int j = 0; j < 16; ++j) {
                    qa[j] = fmaf(a, wq[j], qa[j]);
                    ka[j] = fmaf(a, wk[j], ka[j]);
                }
            }
            #pragma unroll
            for (int j = 0; j < 16; ++j) lds[B0 + (c0 + j) * 64 + lane] = qa[j]; // gQ^T
            __syncthreads();          // hT reads done; gQ^T visible
            #pragma unroll
            for (int j = 0; j < 16; ++j) lds[A + (c0 + j) * 64 + lane] = ka[j];  // gK^T
            __syncthreads();
        }

        if (tid < 126) {              // s[i,i+1] and s[i+1,i]
            int i = tid >> 1, w = tid & 1;
            int ra = w ? i + 1 : i, rb = w ? i : i + 1;
            float s = 0.f;
            #pragma unroll 8
            for (int c2 = 0; c2 < 64; ++c2)
                s = fmaf(lds[B0 + c2 * 64 + ra], lds[A + c2 * 64 + rb], s);
            lds[(w ? M_SDN : M_SU) + i] = s * 0.125f;   // / sqrt(H)
        }
        __syncthreads();

        if (wv == 0) {   // merged: masked softmax + symmetrize + prior + shfl scan
            const int i = lane;
            float mi  = lds[M_MASK + i];
            float mup = (i < 63) ? lds[M_MASK + i + 1] : 0.f;
            float mdn = (i > 0)  ? lds[M_MASK + i - 1] : 0.f;
            float eu = (mi > 0.f && mup > 0.f) ? lds[M_SU + i] : -1e9f;
            float ed = (i > 0 && mi > 0.f && mdn > 0.f) ? lds[M_SDN + i - 1] : -1e9f;
            float m = fmaxf(eu, ed);
            float nu, nd, ng;
            if (m <= -1e9f) { nu = 0.015625f; nd = 0.015625f; ng = 0.015625f; }
            else {
                float zu = __expf(eu - m), zd = __expf(ed - m);
                float iz = 1.f / (zu + zd);
                nu = zu * iz; nd = zd * iz; ng = 0.f;
            }
            float nd1 = __shfl_down(nd, 1);       // nb_dn of row i+1
            float pd = lds[M_PRD + i];
            float dsym = sqrtf(ng * ng + 1e-9f);
            float d2 = pd + (1.f - pd) * dsym;
            lds[M_DVEC + i] = d2; lds[M_PRD + i] = d2;
            float la = 0.f;
            if (i < 63) {
                float pu = lds[M_PRU + i];
                float as_ = sqrtf(nu * nd1 + 1e-9f);
                float a2 = pu + (1.f - pu) * as_;
                la = logf(a2 + 1e-9f);
                lds[M_PRU + i] = __expf(la) + 1e-9f;   // next-layer prior
            }
            float x = __shfl_up(la, 1);
            if (i == 0) x = 0.f;
            #pragma unroll
            for (int off = 1; off < 64; off <<= 1) {
                float t2 = __shfl_up(x, off);
                if (i >= off) x += t2;
            }
            lds[M_S + i] = x;                     // S[i] = sum_{k<i} la[k]
        }
        __syncthreads();

        // ---- MHA: wave wv owns head wv; lane owns row=lane; JIT K/V tiles ----
        LN_STORE(l1g, l1b, lds[A + c_ * 64 + lane] = hv_);
        {
            const int hb = wv << 4;
            const int TB = B0 + wv * 640;      // wave-local K(16x20) + V(16x20) tile
            const int jl = lane & 15, cq = lane >> 4;
            // Q row for this lane (per-head 16 cols)
            float qa[16];
            #pragma unroll
            for (int j = 0; j < 16; ++j) qa[j] = ab[hb + j];
            #pragma unroll 8
            for (int kk = 0; kk < 64; ++kk) {
                float a = lds[A + kk * 64 + lane];
                const float* wq = aw + kk * 64 + hb;
                #pragma unroll
                for (int j = 0; j < 16; ++j) qa[j] = fmaf(a, wq[j], qa[j]);
            }
            float o[16];
            #pragma unroll
            for (int c = 0; c < 16; ++c) o[c] = 0.f;
            float mrun = -1e30f, z = 0.f;
            for (int jt = 0; jt < 4; ++jt) {
                {   // JIT K/V tile: rows jt*16+jl, cols hb+cq*4..+3 (wave-local)
                    float kacc[4], vacc[4];
                    #pragma unroll
                    for (int j = 0; j < 4; ++j) {
                        kacc[j] = ab[64 + hb + (cq << 2) + j];
                        vacc[j] = ab[128 + hb + (cq << 2) + j];
                    }
                    const int row = (jt << 4) + jl;
                    #pragma unroll 8
                    for (int kk = 0; kk < 64; ++kk) {
                        float a = lds[A + kk * 64 + row];
                        const float* wk  = aw + 4096 + kk * 64 + hb + (cq << 2);
                        const float* wvp = aw + 8192 + kk * 64 + hb + (cq << 2);
                        #pragma unroll
                        for (int j = 0; j < 4; ++j) {
                            kacc[j] = fmaf(a, wk[j], kacc[j]);
                            vacc[j] = fmaf(a, wvp[j], vacc[j]);
                        }
                    }
                    *reinterpret_cast<float4*>(&lds[TB + jl * 20 + (cq << 2)]) =
                        make_float4(kacc[0], kacc[1], kacc[2], kacc[3]);
                    *reinterpret_cast<float4*>(&lds[TB + 320 + jl * 20 + (cq << 2)]) =
                        make_float4(vacc[0], vacc[1], vacc[2], vacc[3]);
                    asm volatile("s_waitcnt lgkmcnt(0)" ::: "memory");  // wave-local fence
                }
                #pragma unroll
                for (int half = 0; half < 2; ++half) {
                    float sc[8]; float tm = -1e30f;
                    #pragma unroll
                    for (int jj = 0; jj < 8; ++jj) {
                        const int jloc = (half << 3) + jj;
                        const int j = (jt << 4) + jloc;
                        float s = 0.f;
                        #pragma unroll
                        for (int c4 = 0; c4 < 4; ++c4) {
                            const float4 kv = *reinterpret_cast<const float4*>(
                                &lds[TB + jloc * 20 + (c4 << 2)]);
                            s = fmaf(qa[(c4<<2)+0], kv.x, s); s = fmaf(qa[(c4<<2)+1], kv.y, s);
                            s = fmaf(qa[(c4<<2)+2], kv.z, s); s = fmaf(qa[(c4<<2)+3], kv.w, s);
                        }
                        s = ((mall >> j) & 1ull) ? s * 0.25f : -1e9f;
                        sc[jj] = s; tm = fmaxf(tm, s);
                    }
                    float mn = fmaxf(mrun, tm);
                    float rs = __expf(mrun - mn);
                    z *= rs;
                    #pragma unroll
                    for (int c = 0; c < 16; ++c) o[c] *= rs;
                    mrun = mn;
                    float Sr  = lds[M_S + lane];
                    float dvr = lds[M_DVEC + lane];
                    #pragma unroll
                    for (int jj = 0; jj < 8; ++jj) {
                        const int jloc = (half << 3) + jj;
                        const int j = (jt << 4) + jloc;
                        float e = __expf(sc[jj] - mn);
                        z += e;
                        float Sj = lds[M_S + j];
                        float g = (j == lane) ? dvr
                                  : (__expf((j > lane) ? (Sj - Sr) : (Sr - Sj)) + 1e-9f);
                        float w = e * g;
                        #pragma unroll
                        for (int c4 = 0; c4 < 4; ++c4) {
                            const float4 vv = *reinterpret_cast<const float4*>(
                                &lds[TB + 320 + jloc * 20 + (c4 << 2)]);
                            o[(c4<<2)+0] = fmaf(w, vv.x, o[(c4<<2)+0]);
                            o[(c4<<2)+1] = fmaf(w, vv.y, o[(c4<<2)+1]);
                            o[(c4<<2)+2] = fmaf(w, vv.z, o[(c4<<2)+2]);
                            o[(c4<<2)+3] = fmaf(w, vv.w, o[(c4<<2)+3]);
                        }
                    }
                }
            }
            float iz = 1.f / z;
            __syncthreads();          // all waves' h reads done before O overwrites A
            #pragma unroll
            for (int c = 0; c < 16; ++c) lds[A + lane * 65 + hb + c] = o[c] * iz;
            __syncthreads();
            // O-proj: xr += O @ Wo + bo (O rows stride 65, 2-way free)
            const float* Wo = aw + 12288; const float* bo = ab + 192;
            float acc[16];
            #pragma unroll
            for (int j = 0; j < 16; ++j) acc[j] = bo[c0 + j];
            #pragma unroll 8
            for (int dd = 0; dd < 64; ++dd) {
                float a = lds[A + lane * 65 + dd];
                const float* wr = Wo + dd * 64 + c0;
                #pragma unroll
                for (int j = 0; j < 16; ++j) acc[j] = fmaf(a, wr[j], acc[j]);
            }
            #pragma unroll
            for (int j = 0; j < 16; ++j) xr[j] += acc[j];
        }
        __syncthreads();              // O reads done before FFN LN overwrites A

        // ---- FFN (two 64-col halves of F share one buffer in B0) ----
        LN_STORE(l2g, l2b, lds[A + c_ * 64 + lane] = hv_);
        {   // F-lo
            float fa[16];
            #pragma unroll
            for (int j = 0; j < 16; ++j) fa[j] = fb1[c0 + j];
            #pragma unroll 8
            for (int kk = 0; kk < 64; ++kk) {
                float a = lds[A + kk * 64 + lane];
                const float* wr = fw1 + kk * 128 + c0;
                #pragma unroll
                for (int j = 0; j < 16; ++j) fa[j] = fmaf(a, wr[j], fa[j]);
            }
            #pragma unroll
            for (int j = 0; j < 16; ++j) lds[B0 + (c0 + j) * 64 + lane] = fmaxf(fa[j], 0.f);
        }
        __syncthreads();
        {   // xr += F-lo @ W2[0:64]
            float acc[16];
            #pragma unroll
            for (int j = 0; j < 16; ++j) acc[j] = fb2[c0 + j];
            #pragma unroll 8
            for (int kk = 0; kk < 64; ++kk) {
                float a = lds[B0 + kk * 64 + lane];
                const float* wr = fw2 + kk * 64 + c0;
                #pragma unroll
                for (int j = 0; j < 16; ++j) acc[j] = fmaf(a, wr[j], acc[j]);
            }
            #pragma unroll
            for (int j = 0; j < 16; ++j) xr[j] += acc[j];
        }
        __syncthreads();
        {   // F-hi
            float fa[16];
            #pragma unroll
            for (int j = 0; j < 16; ++j) fa[j] = fb1[64 + c0 + j];
            #pragma unroll 8
            for (int kk = 0; kk < 64; ++kk) {
                float a = lds[A + kk * 64 + lane];
                const float* wr = fw1 + kk * 128 + 64 + c0;
                #pragma unroll
                for (int j = 0; j < 16; ++j) fa[j] = fmaf(a, wr[j], fa[j]);
            }
            #pragma unroll
            for (int j = 0; j < 16; ++j) lds[B0 + (c0 + j) * 64 + lane] = fmaxf(fa[j], 0.f);
        }
        __syncthreads();
        {   // xr += F-hi @ W2[64:128]
            float acc[16];
            #pragma unroll
            for (int j = 0; j < 16; ++j) acc[j] = 0.f;
            #pragma unroll 8
            for (int kk = 0; kk < 64; ++kk) {
                float a = lds[B0 + kk * 64 + lane];
                const float* wr = fw2 + (64 + kk) * 64 + c0;
                #pragma unroll
                for (int j = 0; j < 16; ++j) acc[j] = fmaf(a, wr[j], acc[j]);
            }
            #pragma unroll
            for (int j = 0; j < 16; ++j) xr[j] += acc[j];
        }
        __syncthreads();   // B0 (F) reads done before next LN writes PS into B0
    }

    // ================= reduction / calculator head =================
    LN_STORE(enc_g, enc_b, lds[BH + lane * 65 + c_] = hv_);   // hR stride 65 at B0+512
    if (tid < 64) {       // scores = h @ red_w + red_b + (1-mask)*-1e9
        float s = 0.f;
        #pragma unroll 8
        for (int c2 = 0; c2 < 64; ++c2)
            s = fmaf(lds[BH + tid * 65 + c2], red_w[c2], s);
        s += red_b[0];
        s += (1.f - lds[M_MASK + tid]) * -1e9f;
        lds[M_SU + tid] = s;
    }
    __syncthreads();

    if (wv == 0) {        // softmax, scans, digit assembly (wave 0)
        float s = lds[M_SU + lane];
        float m = s;
        #pragma unroll
        for (int off = 1; off < 64; off <<= 1) m = fmaxf(m, __shfl_xor(m, off));
        float ee = expf(s - m);
        float z = ee;
        #pragma unroll
        for (int off = 1; off < 64; off <<= 1) z += __shfl_xor(z, off);
        float rw = ee / z;
        lds[M_SD + lane] = rw;
        float cum = rw;
        #pragma unroll
        for (int off = 1; off < 64; off <<= 1) { float t2 = __shfl_up(cum, off); if (lane >= off) cum += t2; }
        float isd = lds[M_ISD + lane], dvv = lds[M_DVAL + lane];
        float lm = (1.f - cum) * isd;
        float rm = (cum - rw) * isd;
        float cl = lm;
        #pragma unroll
        for (int off = 1; off < 64; off <<= 1) { float t2 = __shfl_up(cl, off); if (lane >= off) cl += t2; }
        float totl = __shfl(cl, 63);
        float wL = powf(10.f, (totl - cl) * lm) * lm;
        float lv = dvv * wL;
        #pragma unroll
        for (int off = 1; off < 64; off <<= 1) lv += __shfl_xor(lv, off);
        float cr = rm;
        #pragma unroll
        for (int off = 1; off < 64; off <<= 1) { float t2 = __shfl_up(cr, off); if (lane >= off) cr += t2; }
        float totr = __shfl(cr, 63);
        float wR = powf(10.f, (totr - cr) * rm) * rm;
        float rv = dvv * wR;
        #pragma unroll
        for (int off = 1; off < 64; off <<= 1) rv += __shfl_xor(rv, off);
        if (lane == 0) { lds[M_DG + 2] = lv; lds[M_DG + 3] = rv; }
    }
    __syncthreads();

    if (tid < 64) {       // pooled[c] = sum_r h[r][c] * rw[r]
        float p = 0.f;
        #pragma unroll 8
        for (int r2 = 0; r2 < 64; ++r2)
            p = fmaf(lds[BH + r2 * 65 + tid], lds[M_SD + r2], p);
        lds[M_NBU + tid] = p;
    }
    __syncthreads();
    if (tid < 4) {        // op logits
        float s = opc_b[tid];
        for (int c2 = 0; c2 < 64; ++c2) s = fmaf(lds[M_NBU + c2], opc_w[(c2 << 2) + tid], s);
        lds[M_DG + 4 + tid] = s;
    }
    __syncthreads();
    if (tid == 0) {       // hard argmax op select + fixed ops
        float l = lds[M_DG + 2], r = lds[M_DG + 3];
        float o0 = lds[M_DG + 4], o1 = lds[M_DG + 5], o2 = lds[M_DG + 6], o3 = lds[M_DG + 7];
        int op = 0; float bm = o0;
        if (o1 > bm) { bm = o1; op = 1; }
        if (o2 > bm) { bm = o2; op = 2; }
        if (o3 > bm) { bm = o3; op = 3; }
        float res, vl = 1.f;
        if (op == 0)      res = l + r;
        else if (op == 1) res = l - r;
        else if (op == 2) res = l * r;
        else { bool bad = fabsf(r) < 1e-6f; res = bad ? 0.f : (l / r); vl = bad ? 0.f : 1.f; }
        float rc = (res > 0.f) ? log1pf(res) : ((res < 0.f) ? -log1pf(-res) : 0.f);
        lds[M_DG + 0] = rc; lds[M_DG + 1] = vl;
        out[O_RES + b]   = res;
        out[O_VALID + b] = vl;
        out[O_LEFT + b]  = l;
        out[O_RIGHT + b] = r;
    }
    __syncthreads();
    if (tid < 64) {
        float rc = lds[M_DG + 0], vl = lds[M_DG + 1];
        out[O_REMB + (b << 6) + tid] = rc * res_w[tid] + vl * res_w[64 + tid] + res_b[tid];
        out[O_RW + (b << 6) + tid] = lds[M_SD + tid];
    }
    if (tid >= 64 && tid < 68) {
        int o = tid - 64;
        out[O_OPL + (b << 2) + o] = lds[M_DG + 4 + o];
    }
}

extern "C" void kernel_launch(void* const* d_in, const int* in_sizes, int n_in,
                              void* d_out, int out_size, void* d_ws, size_t ws_size,
                              hipStream_t stream)
{
    fsa_kernel<<<dim3(BATCH), dim3(256), 0, stream>>>(
        (const int*)d_in[0],
        (const float*)d_in[1],  (const float*)d_in[2],  (const float*)d_in[3],
        (const float*)d_in[4],  (const float*)d_in[5],  (const float*)d_in[6],  (const float*)d_in[7],
        (const float*)d_in[8],  (const float*)d_in[9],  (const float*)d_in[10], (const float*)d_in[11],
        (const float*)d_in[12], (const float*)d_in[13], (const float*)d_in[14], (const float*)d_in[15],
        (const float*)d_in[16], (const float*)d_in[17], (const float*)d_in[18], (const float*)d_in[19],
        (const float*)d_in[20], (const float*)d_in[21], (const float*)d_in[22], (const float*)d_in[23],
        (const float*)d_in[24], (const float*)d_in[25], (const float*)d_in[26], (const float*)d_in[27],
        (float*)d_out);
}